// Round 16
// baseline (320.009 us; speedup 1.0000x reference)
//
#include <hip/hip_runtime.h>
#include <hip/hip_bf16.h>

typedef __bf16 bf16;
typedef __attribute__((ext_vector_type(8))) __bf16 bf16x8;
typedef __attribute__((ext_vector_type(4))) float f32x4;

#define SCALE2 (0.08838834764831845f * 1.4426950408889634f)  // log2(e)/sqrt(128)

__device__ inline void gload16(const bf16* g, bf16* l) {
  __builtin_amdgcn_global_load_lds((const __attribute__((address_space(1))) void*)g,
                                   (__attribute__((address_space(3))) void*)l, 16, 0, 0);
}

// ---------------- f32 -> bf16 convert (8 elems/thread) ----------------
__global__ void cvt_kernel(const float* __restrict__ in, bf16* __restrict__ out, int n8) {
  int i = blockIdx.x * 256 + threadIdx.x;
  if (i >= n8) return;
  const float* p = in + (size_t)i * 8;
  float4 a = *(const float4*)p, b = *(const float4*)(p + 4);
  union { uint4 u; bf16 h[8]; } un;
  un.h[0] = (bf16)a.x; un.h[1] = (bf16)a.y; un.h[2] = (bf16)a.z; un.h[3] = (bf16)a.w;
  un.h[4] = (bf16)b.x; un.h[5] = (bf16)b.y; un.h[6] = (bf16)b.z; un.h[7] = (bf16)b.w;
  *(uint4*)(out + (size_t)i * 8) = un.u;
}

// ---------------- bias concat (f32): [bq(2048) | bk(512) | bv(512)] ----------------
__global__ void concat_bias_kernel(const float* __restrict__ bq, const float* __restrict__ bk,
                                   const float* __restrict__ bv, float* __restrict__ o) {
  int i = blockIdx.x * 256 + threadIdx.x;
  if (i >= 3072) return;
  o[i] = (i < 2048) ? bq[i] : (i < 2560 ? bk[i - 2048] : bv[i - 2560]);
}

// ---------------- transpose+convert: in f32 [K][N] -> out bf16 [N][K] (64x64 tiles) --------
__global__ __launch_bounds__(256)
void transpose_cvt_kernel(const float* __restrict__ in, bf16* __restrict__ out, int K, int N) {
  __shared__ bf16 tile[64][72];
  int n0 = blockIdx.x * 64, k0 = blockIdx.y * 64;
  int t = threadIdx.x;
  int r8 = t >> 5, c2 = (t & 31) * 2;
#pragma unroll
  for (int it = 0; it < 8; it++) {
    int row = it * 8 + r8;
    float2 v = *(const float2*)(in + (size_t)(k0 + row) * N + n0 + c2);
    tile[row][c2] = (bf16)v.x;
    tile[row][c2 + 1] = (bf16)v.y;
  }
  __syncthreads();
  int r = t >> 3, c = (t & 7) * 8;
  int rot = t & 7;
#pragma unroll
  for (int it = 0; it < 2; it++) {
    int rr = it * 32 + r;
    union { uint4 u; bf16 h[8]; } un;
#pragma unroll
    for (int j = 0; j < 8; j++) {
      int jj = (j + rot) & 7;
      un.h[jj] = tile[c + jj][rr];   // = in[k0+c+jj][n0+rr]
    }
    *(uint4*)(out + (size_t)(n0 + rr) * K + k0 + c) = un.u;
  }
}

// ---------------- V transpose (bf16): qkv v-region [T][128] -> vT[(b*4+kvh)*128+d][2048] ----
__global__ __launch_bounds__(256)
void transpose_v_kernel(const bf16* __restrict__ qkv, bf16* __restrict__ vT) {
  __shared__ bf16 tile[64][72];
  int z = blockIdx.z;              // b*4+kvh
  int b = z >> 2, kvh = z & 3;
  int d0 = blockIdx.y * 64;        // 0 or 64
  int t0 = blockIdx.x * 64;        // 0..31 * 64
  const bf16* in = qkv + (size_t)(b * 2048) * 3072 + 2560 + kvh * 128;
  int t = threadIdx.x;
  int r = t >> 3, c = (t & 7) * 8;
#pragma unroll
  for (int it = 0; it < 2; it++) {
    int rr = it * 32 + r;          // t-row
    *(uint4*)&tile[rr][c] = *(const uint4*)(in + (size_t)(t0 + rr) * 3072 + d0 + c);
  }
  __syncthreads();
  int rot = t & 7;
#pragma unroll
  for (int it = 0; it < 2; it++) {
    int rr = it * 32 + r;          // d-row of output
    union { uint4 u; bf16 h[8]; } un;
#pragma unroll
    for (int j = 0; j < 8; j++) {
      int jj = (j + rot) & 7;
      un.h[jj] = tile[c + jj][rr]; // = in[t0+c+jj][d0+rr]
    }
    *(uint4*)(vT + (size_t)(z * 128 + d0 + rr) * 2048 + t0 + c) = un.u;
  }
}

// ---------------- RoPE tables: cos/sin [2048][64] f32 ----------------
__global__ void rope_table_kernel(float* __restrict__ cost, float* __restrict__ sint) {
  int idx = blockIdx.x * 256 + threadIdx.x;   // 2048*64
  int t = idx >> 6, i = idx & 63;
  float inv = expf(-(float)i * (logf(10000.f) / 64.f));
  float ang = (float)t * inv;
  cost[idx] = cosf(ang);
  sint[idx] = sinf(ang);
}

// ---------------- RoPE apply in-place on qkv[row][0..2560) (q then k region) ----------------
__global__ void rope_apply_kernel(bf16* __restrict__ qkv, const float* __restrict__ cost,
                                  const float* __restrict__ sint) {
  int p = blockIdx.x * 256 + threadIdx.x;     // 4096 * 320 chunks of 8 elems (4 pairs)
  if (p >= 4096 * 320) return;
  int row = p / 320;
  int rc = p - row * 320;
  int e = rc * 8;                              // element col in [0,2560)
  int t = row & 2047;
  int i0 = (e & 127) >> 1;                     // pair index within head (mult of 4)
  bf16* ptr = qkv + (size_t)row * 3072 + e;
  float4 cv = *(const float4*)(cost + t * 64 + i0);
  float4 sv = *(const float4*)(sint + t * 64 + i0);
  float c[4] = {cv.x, cv.y, cv.z, cv.w}, s[4] = {sv.x, sv.y, sv.z, sv.w};
  union { uint4 u; bf16 h[8]; } un;
  un.u = *(const uint4*)ptr;
#pragma unroll
  for (int j = 0; j < 4; j++) {
    float x0 = (float)un.h[2 * j], x1 = (float)un.h[2 * j + 1];
    un.h[2 * j]     = (bf16)(x0 * c[j] - x1 * s[j]);
    un.h[2 * j + 1] = (bf16)(x1 * c[j] + x0 * s[j]);
  }
  *(uint4*)ptr = un.u;
}

// ---------------- GEMM: C[M][ldc] = A[M][K] * Bt[N][K]^T + bias(f32) ------
// BK=32 double-buffer + both-sides chunk swizzle + bijective XCD swizzle. (round-12, kept)
template <typename OutT>
__global__ __launch_bounds__(256)
void gemm_bias_kernel(const bf16* __restrict__ A, const bf16* __restrict__ Bt,
                      const float* __restrict__ bias, OutT* __restrict__ C,
                      int M, int N, int K, int lda, int ldc) {
  __shared__ bf16 As[2][128 * 32];
  __shared__ bf16 Bs[2][128 * 32];
  int tid = threadIdx.x;
  int wv = tid >> 6, l = tid & 63;
  int wr = wv >> 1, wc = wv & 1;
  int lr = l & 15, g = l >> 4;

  int bid = blockIdx.y * gridDim.x + blockIdx.x;
  int cpx = (gridDim.x * gridDim.y) >> 3;
  int swz = (bid & 7) * cpx + (bid >> 3);
  int m0 = (swz / gridDim.x) * 128, n0 = (swz % gridDim.x) * 128;

  auto stage = [&](int k0, int buf) {
#pragma unroll
    for (int i = 0; i < 2; i++) {
      int e = i * 256 + tid;
      int row = e >> 2, c = e & 3;
      int csrc = (c ^ ((row >> 1) & 3)) * 8;
      gload16(A + (size_t)(m0 + row) * lda + k0 + csrc, &As[buf][(size_t)e * 8]);
      gload16(Bt + (size_t)(n0 + row) * K + k0 + csrc, &Bs[buf][(size_t)e * 8]);
    }
  };

  f32x4 acc[4][4] = {};
  stage(0, 0);
  __syncthreads();
  int cur = 0;
  int cswz = (g ^ ((lr >> 1) & 3)) * 8;
  for (int k0 = 32; k0 <= K; k0 += 32) {
    if (k0 < K) stage(k0, cur ^ 1);
    bf16x8 a[4], b[4];
#pragma unroll
    for (int mi = 0; mi < 4; mi++)
      a[mi] = *(const bf16x8*)&As[cur][(size_t)(wr * 64 + mi * 16 + lr) * 32 + cswz];
#pragma unroll
    for (int nj = 0; nj < 4; nj++)
      b[nj] = *(const bf16x8*)&Bs[cur][(size_t)(wc * 64 + nj * 16 + lr) * 32 + cswz];
#pragma unroll
    for (int mi = 0; mi < 4; mi++)
#pragma unroll
      for (int nj = 0; nj < 4; nj++)
        acc[mi][nj] = __builtin_amdgcn_mfma_f32_16x16x32_bf16(a[mi], b[nj], acc[mi][nj], 0, 0, 0);
    __syncthreads();
    cur ^= 1;
  }
#pragma unroll
  for (int nj = 0; nj < 4; nj++) {
    int gc = n0 + wc * 64 + nj * 16 + lr;
    float bv = bias[gc];
#pragma unroll
    for (int mi = 0; mi < 4; mi++) {
      int gr = m0 + wr * 64 + mi * 16 + g * 4;
#pragma unroll
      for (int reg = 0; reg < 4; reg++)
        C[(size_t)(gr + reg) * ldc + gc] = (OutT)(acc[mi][nj][reg] + bv);
    }
  }
}

// ---- Flash attention (causal, GQA): 8-wave piggyback with ADJACENT pairing {2p+1, 2p}
//      (group-1 idles only the last iter: 97% slot utilization vs 67% for {31-p,p}).
//      r13 schedule: K single-buf + V^T double-buf, both staged post-barA (covered by
//      softmax+PV). Swapped QK^T, in-register softmax + defer-max, pre-scaled Q. ----
__global__ __launch_bounds__(512, 4)
void attn_kernel(const bf16* __restrict__ qkv, const bf16* __restrict__ vT,
                 bf16* __restrict__ ybuf) {
  __shared__ bf16 Ks[64 * 128];       // K single-buf [kpos][d], chunk-swizzled c^=(row&7)
  __shared__ bf16 Vts[2][128 * 64];   // V^T dbuf [d][s], chunk-swizzled c^=(row&7)
  __shared__ bf16 Ps[8][16][72];      // per-wave P tile [q-row][k], padded

  int pair = blockIdx.x;          // 0..15
  int bh = blockIdx.y;            // 0..31
  int b = bh >> 4, h = bh & 15;
  int kvh = h >> 2;               // G=4
  int tid = threadIdx.x, w = tid >> 6, l = tid & 63;
  int lr = l & 15, g = l >> 4, lk = g * 8;
  int wl = w & 3, wg = w >> 2;
  int qt = wg ? 2 * pair : 2 * pair + 1;   // adjacent tiles; group 0 -> the longer one
  int q0 = qt * 64;
  int nt = 2 * pair + 2;                   // iterations (group 1 idles only the last)

  const bf16* kbase = qkv + (size_t)(b * 2048) * 3072 + 2048 + kvh * 128;
  const bf16* vtb   = vT + (size_t)(b * 4 + kvh) * 128 * 2048;
  f32x4 zero4 = {0.f, 0.f, 0.f, 0.f};

  // K tile: 1024 16B-chunks; V^T tile: 1024 chunks. 512 threads -> 2 each.
  auto stageK = [&](int kv0) {
#pragma unroll
    for (int it = 0; it < 2; it++) {
      int cidx = it * 512 + tid;
      int row = cidx >> 4, c = cidx & 15, csrc = c ^ (row & 7);
      gload16(kbase + (size_t)(kv0 + row) * 3072 + csrc * 8, &Ks[(size_t)cidx * 8]);
    }
  };
  auto stageV = [&](int kv0, int buf) {
#pragma unroll
    for (int it = 0; it < 2; it++) {
      int cidx = it * 512 + tid;
      int row = cidx >> 3, c = cidx & 7, csrc = c ^ (row & 7);
      gload16(vtb + (size_t)row * 2048 + kv0 + csrc * 8, &Vts[buf][(size_t)cidx * 8]);
    }
  };

  // Q fragments (post-RoPE), pre-scaled by log2(e)/sqrt(D)
  const bf16* qbase = qkv + (size_t)(b * 2048 + q0 + wl * 16 + lr) * 3072 + h * 128;
  bf16x8 qf[4];
#pragma unroll
  for (int kk = 0; kk < 4; kk++) {
    bf16x8 v = *(const bf16x8*)(qbase + kk * 32 + lk);
#pragma unroll
    for (int j = 0; j < 8; j++) v[j] = (bf16)((float)v[j] * SCALE2);
    qf[kk] = v;
  }

  float m_r = -1e30f, l_r = 0.f;      // per-lane scalars (q-row lr)
  f32x4 o_acc[8];
#pragma unroll
  for (int f = 0; f < 8; f++) o_acc[f] = zero4;

  stageK(0);
  stageV(0, 0);
  __syncthreads();                 // drains vmcnt(0): tile 0 resident
  int cur = 0;

  for (int kvt = 0; kvt < nt; kvt++) {
    int kv0 = kvt * 64;
    bool act = (kvt <= qt);        // wave-uniform; group 1 idles only at kvt = nt-1

    // S^T = K Q^T (swapped): sa[nj][rg] = S[q=lr][k=nj*16+g*4+rg]  (pre-scaled)
    f32x4 sa[4];
#pragma unroll
    for (int nj = 0; nj < 4; nj++) sa[nj] = zero4;
    if (act) {
#pragma unroll
      for (int kk = 0; kk < 4; kk++) {
        int cmem = (kk * 4 + g) ^ (lr & 7);
#pragma unroll
        for (int nj = 0; nj < 4; nj++) {
          bf16x8 kf = *(const bf16x8*)&Ks[(size_t)((nj * 16 + lr) * 16 + cmem) * 8];
          sa[nj] = __builtin_amdgcn_mfma_f32_16x16x32_bf16(kf, qf[kk], sa[nj], 0, 0, 0);
        }
      }
    }
    __syncthreads();               // barA: all QK reads of Ks done

    // stage next tile (K sbuf now safe; V into other dbuf half); drains at barB,
    // covered by softmax+PV below.
    if (kvt + 1 < nt) {
      stageK(kv0 + 64);
      stageV(kv0 + 64, cur ^ 1);
    }

    if (act) {
      bool diag = (kvt == qt);
      int qpos = q0 + wl * 16 + lr;
      float p[4][4];
#pragma unroll
      for (int nj = 0; nj < 4; nj++)
#pragma unroll
        for (int rg = 0; rg < 4; rg++) {
          float s = sa[nj][rg];
          if (diag && (kv0 + nj * 16 + g * 4 + rg > qpos)) s = -1e30f;
          p[nj][rg] = s;
        }

      // row max (local tree + 2 shuffles)
      float a0 = fmaxf(fmaxf(p[0][0], p[0][1]), fmaxf(p[0][2], p[0][3]));
      float a1 = fmaxf(fmaxf(p[1][0], p[1][1]), fmaxf(p[1][2], p[1][3]));
      float a2 = fmaxf(fmaxf(p[2][0], p[2][1]), fmaxf(p[2][2], p[2][3]));
      float a3 = fmaxf(fmaxf(p[3][0], p[3][1]), fmaxf(p[3][2], p[3][3]));
      float mx = fmaxf(fmaxf(a0, a1), fmaxf(a2, a3));
      mx = fmaxf(mx, __shfl_xor(mx, 16));
      mx = fmaxf(mx, __shfl_xor(mx, 32));

      // defer-max (T13): rescale only when max grew past threshold (log2 domain)
      if (__any(mx > m_r + 8.0f)) {
        float mnew = fmaxf(m_r, mx);
        float sc = exp2f(m_r - mnew);
        l_r *= sc;
        m_r = mnew;
        float osc[4];
#pragma unroll
        for (int rg = 0; rg < 4; rg++) osc[rg] = __shfl(sc, g * 4 + rg);
#pragma unroll
        for (int f = 0; f < 8; f++)
#pragma unroll
          for (int rg = 0; rg < 4; rg++) o_acc[f][rg] *= osc[rg];
      }

#pragma unroll
      for (int nj = 0; nj < 4; nj++)
#pragma unroll
        for (int rg = 0; rg < 4; rg++) p[nj][rg] = exp2f(p[nj][rg] - m_r);
      float s0 = (p[0][0] + p[0][1]) + (p[0][2] + p[0][3]);
      float s1 = (p[1][0] + p[1][1]) + (p[1][2] + p[1][3]);
      float s2 = (p[2][0] + p[2][1]) + (p[2][2] + p[2][3]);
      float s3 = (p[3][0] + p[3][1]) + (p[3][2] + p[3][3]);
      float rs = (s0 + s1) + (s2 + s3);
      rs += __shfl_xor(rs, 16);
      rs += __shfl_xor(rs, 32);
      l_r += rs;

      // P -> LDS (b64 writes)
#pragma unroll
      for (int nj = 0; nj < 4; nj++) {
        union { uint2 u; bf16 hh[4]; } pw;
#pragma unroll
        for (int rg = 0; rg < 4; rg++) pw.hh[rg] = (bf16)p[nj][rg];
        *(uint2*)&Ps[w][lr][nj * 16 + g * 4] = pw.u;
      }
      asm volatile("s_waitcnt lgkmcnt(0)" ::: "memory");
      __builtin_amdgcn_sched_barrier(0);

      // O += P V  (V[kvt] in Vts[cur])
#pragma unroll
      for (int kk2 = 0; kk2 < 2; kk2++) {
        bf16x8 pf = *(const bf16x8*)&Ps[w][lr][kk2 * 32 + lk];
        int cmem = (kk2 * 4 + g) ^ (lr & 7);
#pragma unroll
        for (int f = 0; f < 8; f++) {
          bf16x8 vf = *(const bf16x8*)&Vts[cur][(size_t)((f * 16 + lr) * 8 + cmem) * 8];
          o_acc[f] = __builtin_amdgcn_mfma_f32_16x16x32_bf16(pf, vf, o_acc[f], 0, 0, 0);
        }
      }
    }
    __syncthreads();               // barB: drains next-tile DMA; PV reads done
    cur ^= 1;
  }

  // epilogue: O / l -> ybuf; row r=g*4+rg's l lives in lane r
  float linv[4];
#pragma unroll
  for (int rg = 0; rg < 4; rg++) linv[rg] = 1.0f / __shfl(l_r, g * 4 + rg);
  size_t orow = (size_t)(b * 2048 + q0 + wl * 16);
#pragma unroll
  for (int rg = 0; rg < 4; rg++) {
    int r = g * 4 + rg;
#pragma unroll
    for (int f = 0; f < 8; f++) {
      float ov = o_acc[f][rg] * linv[rg];
      ybuf[(orow + r) * 2048 + h * 128 + f * 16 + lr] = (bf16)ov;
    }
  }
}

// ---------------- host launch ----------------
extern "C" void kernel_launch(void* const* d_in, const int* in_sizes, int n_in,
                              void* d_out, int out_size, void* d_ws, size_t ws_size,
                              hipStream_t stream) {
  const float* x  = (const float*)d_in[0];
  const float* Wq = (const float*)d_in[1];
  const float* bq = (const float*)d_in[2];
  const float* Wk = (const float*)d_in[3];
  const float* bk = (const float*)d_in[4];
  const float* Wv = (const float*)d_in[5];
  const float* bv = (const float*)d_in[6];
  const float* Wo = (const float*)d_in[7];
  const float* bo = (const float*)d_in[8];
  float* out = (float*)d_out;

  char* w = (char*)d_ws;
  auto alloc = [&](size_t bytes) { char* p = w; w += (bytes + 255) & ~(size_t)255; return p; };
  bf16*  xb    = (bf16*)alloc((size_t)4096 * 2048 * 2);
  bf16*  wqkvT = (bf16*)alloc((size_t)3072 * 2048 * 2);
  bf16*  qkv   = (bf16*)alloc((size_t)4096 * 3072 * 2);
  bf16*  vTg   = (bf16*)alloc((size_t)8 * 128 * 2048 * 2);   // [b*4+kvh][128][2048]
  float* bqkv  = (float*)alloc((size_t)3072 * 4);
  float* cost  = (float*)alloc((size_t)2048 * 64 * 4);
  float* sint  = (float*)alloc((size_t)2048 * 64 * 4);
  bf16*  ybuf  = xb;      // alias: xb dead before attn writes ybuf
  bf16*  woT   = wqkvT;   // alias: wqkvT dead before Wo transpose runs

  cvt_kernel<<<4096, 256, 0, stream>>>(x, xb, 4096 * 2048 / 8);
  concat_bias_kernel<<<12, 256, 0, stream>>>(bq, bk, bv, bqkv);
  transpose_cvt_kernel<<<dim3(32, 32), 256, 0, stream>>>(Wq, wqkvT, 2048, 2048);
  transpose_cvt_kernel<<<dim3(8, 32), 256, 0, stream>>>(Wk, wqkvT + (size_t)2048 * 2048, 2048, 512);
  transpose_cvt_kernel<<<dim3(8, 32), 256, 0, stream>>>(Wv, wqkvT + (size_t)2560 * 2048, 2048, 512);
  rope_table_kernel<<<512, 256, 0, stream>>>(cost, sint);
  gemm_bias_kernel<bf16><<<dim3(24, 32), 256, 0, stream>>>(xb, wqkvT, bqkv, qkv, 4096, 3072, 2048, 2048, 3072);
  transpose_cvt_kernel<<<dim3(32, 32), 256, 0, stream>>>(Wo, woT, 2048, 2048);
  transpose_v_kernel<<<dim3(32, 2, 8), 256, 0, stream>>>(qkv, vTg);
  rope_apply_kernel<<<5120, 256, 0, stream>>>(qkv, cost, sint);
  attn_kernel<<<dim3(16, 32), 512, 0, stream>>>(qkv, vTg, ybuf);
  gemm_bias_kernel<float><<<dim3(16, 32), 256, 0, stream>>>(ybuf, woT, bo, out, 4096, 2048, 2048, 2048, 2048);
}

// Round 17
// 297.354 us; speedup vs baseline: 1.0762x; 1.0762x over previous
//
#include <hip/hip_runtime.h>
#include <hip/hip_bf16.h>

typedef __bf16 bf16;
typedef __attribute__((ext_vector_type(8))) __bf16 bf16x8;
typedef __attribute__((ext_vector_type(4))) float f32x4;

#define SCALE2 (0.08838834764831845f * 1.4426950408889634f)  // log2(e)/sqrt(128)

__device__ inline void gload16(const bf16* g, bf16* l) {
  __builtin_amdgcn_global_load_lds((const __attribute__((address_space(1))) void*)g,
                                   (__attribute__((address_space(3))) void*)l, 16, 0, 0);
}

// ---------------- f32 -> bf16 convert (8 elems/thread) ----------------
__global__ void cvt_kernel(const float* __restrict__ in, bf16* __restrict__ out, int n8) {
  int i = blockIdx.x * 256 + threadIdx.x;
  if (i >= n8) return;
  const float* p = in + (size_t)i * 8;
  float4 a = *(const float4*)p, b = *(const float4*)(p + 4);
  union { uint4 u; bf16 h[8]; } un;
  un.h[0] = (bf16)a.x; un.h[1] = (bf16)a.y; un.h[2] = (bf16)a.z; un.h[3] = (bf16)a.w;
  un.h[4] = (bf16)b.x; un.h[5] = (bf16)b.y; un.h[6] = (bf16)b.z; un.h[7] = (bf16)b.w;
  *(uint4*)(out + (size_t)i * 8) = un.u;
}

// ---------------- bias concat (f32): [bq(2048) | bk(512) | bv(512)] ----------------
__global__ void concat_bias_kernel(const float* __restrict__ bq, const float* __restrict__ bk,
                                   const float* __restrict__ bv, float* __restrict__ o) {
  int i = blockIdx.x * 256 + threadIdx.x;
  if (i >= 3072) return;
  o[i] = (i < 2048) ? bq[i] : (i < 2560 ? bk[i - 2048] : bv[i - 2560]);
}

// ---------------- transpose+convert: in f32 [K][N] -> out bf16 [N][K] (64x64 tiles) --------
__global__ __launch_bounds__(256)
void transpose_cvt_kernel(const float* __restrict__ in, bf16* __restrict__ out, int K, int N) {
  __shared__ bf16 tile[64][72];
  int n0 = blockIdx.x * 64, k0 = blockIdx.y * 64;
  int t = threadIdx.x;
  int r8 = t >> 5, c2 = (t & 31) * 2;
#pragma unroll
  for (int it = 0; it < 8; it++) {
    int row = it * 8 + r8;
    float2 v = *(const float2*)(in + (size_t)(k0 + row) * N + n0 + c2);
    tile[row][c2] = (bf16)v.x;
    tile[row][c2 + 1] = (bf16)v.y;
  }
  __syncthreads();
  int r = t >> 3, c = (t & 7) * 8;
  int rot = t & 7;
#pragma unroll
  for (int it = 0; it < 2; it++) {
    int rr = it * 32 + r;
    union { uint4 u; bf16 h[8]; } un;
#pragma unroll
    for (int j = 0; j < 8; j++) {
      int jj = (j + rot) & 7;
      un.h[jj] = tile[c + jj][rr];   // = in[k0+c+jj][n0+rr]
    }
    *(uint4*)(out + (size_t)(n0 + rr) * K + k0 + c) = un.u;
  }
}

// ---------------- V transpose (bf16): qkv v-region [T][128] -> vT[(b*4+kvh)*128+d][2048] ----
__global__ __launch_bounds__(256)
void transpose_v_kernel(const bf16* __restrict__ qkv, bf16* __restrict__ vT) {
  __shared__ bf16 tile[64][72];
  int z = blockIdx.z;              // b*4+kvh
  int b = z >> 2, kvh = z & 3;
  int d0 = blockIdx.y * 64;        // 0 or 64
  int t0 = blockIdx.x * 64;        // 0..31 * 64
  const bf16* in = qkv + (size_t)(b * 2048) * 3072 + 2560 + kvh * 128;
  int t = threadIdx.x;
  int r = t >> 3, c = (t & 7) * 8;
#pragma unroll
  for (int it = 0; it < 2; it++) {
    int rr = it * 32 + r;          // t-row
    *(uint4*)&tile[rr][c] = *(const uint4*)(in + (size_t)(t0 + rr) * 3072 + d0 + c);
  }
  __syncthreads();
  int rot = t & 7;
#pragma unroll
  for (int it = 0; it < 2; it++) {
    int rr = it * 32 + r;          // d-row of output
    union { uint4 u; bf16 h[8]; } un;
#pragma unroll
    for (int j = 0; j < 8; j++) {
      int jj = (j + rot) & 7;
      un.h[jj] = tile[c + jj][rr]; // = in[t0+c+jj][d0+rr]
    }
    *(uint4*)(vT + (size_t)(z * 128 + d0 + rr) * 2048 + t0 + c) = un.u;
  }
}

// ---------------- RoPE tables: cos/sin [2048][64] f32 ----------------
__global__ void rope_table_kernel(float* __restrict__ cost, float* __restrict__ sint) {
  int idx = blockIdx.x * 256 + threadIdx.x;   // 2048*64
  int t = idx >> 6, i = idx & 63;
  float inv = expf(-(float)i * (logf(10000.f) / 64.f));
  float ang = (float)t * inv;
  cost[idx] = cosf(ang);
  sint[idx] = sinf(ang);
}

// ---------------- RoPE apply in-place on qkv[row][0..2560) (q then k region) ----------------
__global__ void rope_apply_kernel(bf16* __restrict__ qkv, const float* __restrict__ cost,
                                  const float* __restrict__ sint) {
  int p = blockIdx.x * 256 + threadIdx.x;     // 4096 * 320 chunks of 8 elems (4 pairs)
  if (p >= 4096 * 320) return;
  int row = p / 320;
  int rc = p - row * 320;
  int e = rc * 8;                              // element col in [0,2560)
  int t = row & 2047;
  int i0 = (e & 127) >> 1;                     // pair index within head (mult of 4)
  bf16* ptr = qkv + (size_t)row * 3072 + e;
  float4 cv = *(const float4*)(cost + t * 64 + i0);
  float4 sv = *(const float4*)(sint + t * 64 + i0);
  float c[4] = {cv.x, cv.y, cv.z, cv.w}, s[4] = {sv.x, sv.y, sv.z, sv.w};
  union { uint4 u; bf16 h[8]; } un;
  un.u = *(const uint4*)ptr;
#pragma unroll
  for (int j = 0; j < 4; j++) {
    float x0 = (float)un.h[2 * j], x1 = (float)un.h[2 * j + 1];
    un.h[2 * j]     = (bf16)(x0 * c[j] - x1 * s[j]);
    un.h[2 * j + 1] = (bf16)(x1 * c[j] + x0 * s[j]);
  }
  *(uint4*)ptr = un.u;
}

// ---------------- GEMM: C[M][ldc] = A[M][K] * Bt[N][K]^T + bias(f32) ------
// BK=32 double-buffer + both-sides chunk swizzle + bijective XCD swizzle. (round-12, kept)
template <typename OutT>
__global__ __launch_bounds__(256)
void gemm_bias_kernel(const bf16* __restrict__ A, const bf16* __restrict__ Bt,
                      const float* __restrict__ bias, OutT* __restrict__ C,
                      int M, int N, int K, int lda, int ldc) {
  __shared__ bf16 As[2][128 * 32];
  __shared__ bf16 Bs[2][128 * 32];
  int tid = threadIdx.x;
  int wv = tid >> 6, l = tid & 63;
  int wr = wv >> 1, wc = wv & 1;
  int lr = l & 15, g = l >> 4;

  int bid = blockIdx.y * gridDim.x + blockIdx.x;
  int cpx = (gridDim.x * gridDim.y) >> 3;
  int swz = (bid & 7) * cpx + (bid >> 3);
  int m0 = (swz / gridDim.x) * 128, n0 = (swz % gridDim.x) * 128;

  auto stage = [&](int k0, int buf) {
#pragma unroll
    for (int i = 0; i < 2; i++) {
      int e = i * 256 + tid;
      int row = e >> 2, c = e & 3;
      int csrc = (c ^ ((row >> 1) & 3)) * 8;
      gload16(A + (size_t)(m0 + row) * lda + k0 + csrc, &As[buf][(size_t)e * 8]);
      gload16(Bt + (size_t)(n0 + row) * K + k0 + csrc, &Bs[buf][(size_t)e * 8]);
    }
  };

  f32x4 acc[4][4] = {};
  stage(0, 0);
  __syncthreads();
  int cur = 0;
  int cswz = (g ^ ((lr >> 1) & 3)) * 8;
  for (int k0 = 32; k0 <= K; k0 += 32) {
    if (k0 < K) stage(k0, cur ^ 1);
    bf16x8 a[4], b[4];
#pragma unroll
    for (int mi = 0; mi < 4; mi++)
      a[mi] = *(const bf16x8*)&As[cur][(size_t)(wr * 64 + mi * 16 + lr) * 32 + cswz];
#pragma unroll
    for (int nj = 0; nj < 4; nj++)
      b[nj] = *(const bf16x8*)&Bs[cur][(size_t)(wc * 64 + nj * 16 + lr) * 32 + cswz];
#pragma unroll
    for (int mi = 0; mi < 4; mi++)
#pragma unroll
      for (int nj = 0; nj < 4; nj++)
        acc[mi][nj] = __builtin_amdgcn_mfma_f32_16x16x32_bf16(a[mi], b[nj], acc[mi][nj], 0, 0, 0);
    __syncthreads();
    cur ^= 1;
  }
#pragma unroll
  for (int nj = 0; nj < 4; nj++) {
    int gc = n0 + wc * 64 + nj * 16 + lr;
    float bv = bias[gc];
#pragma unroll
    for (int mi = 0; mi < 4; mi++) {
      int gr = m0 + wr * 64 + mi * 16 + g * 4;
#pragma unroll
      for (int reg = 0; reg < 4; reg++)
        C[(size_t)(gr + reg) * ldc + gc] = (OutT)(acc[mi][nj][reg] + bv);
    }
  }
}

// ---- Flash attention (causal, GQA): r13 schedule ({31-p,p} piggyback, K sbuf + V dbuf
//      staged post-barA) with REGISTER-ONLY P re-fragmentation: P->PV fragment via 16
//      dword shuffles (no Ps LDS, no lgkmcnt serializer). LDS 48KB -> 3 blocks/CU. ----
// Shuffle map: pf(kk2)[0..7] = P[lr][kk2*32+g*8 .. +7]; nj_src = 2*kk2+(g>>1);
// low 4 from lane 2*(g&1)*16+lr, high 4 from +16. Lane matches nj in {g>>1, 2+(g>>1)}.
__global__ __launch_bounds__(512, 4)
void attn_kernel(const bf16* __restrict__ qkv, const bf16* __restrict__ vT,
                 bf16* __restrict__ ybuf) {
  __shared__ bf16 Ks[64 * 128];       // K single-buf [kpos][d], chunk-swizzled c^=(row&7)
  __shared__ bf16 Vts[2][128 * 64];   // V^T dbuf [d][s], chunk-swizzled c^=(row&7)

  int pair = blockIdx.x;          // 0..15
  int bh = blockIdx.y;            // 0..31
  int b = bh >> 4, h = bh & 15;
  int kvh = h >> 2;               // G=4
  int tid = threadIdx.x, w = tid >> 6, l = tid & 63;
  int lr = l & 15, g = l >> 4, lk = g * 8;
  int wl = w & 3, wg = w >> 2;
  int qt = wg ? pair : 31 - pair;       // group 0 -> long tile
  int q0 = qt * 64;
  int nt = 32 - pair;                   // iterations (max over both groups)

  const bf16* kbase = qkv + (size_t)(b * 2048) * 3072 + 2048 + kvh * 128;
  const bf16* vtb   = vT + (size_t)(b * 4 + kvh) * 128 * 2048;
  f32x4 zero4 = {0.f, 0.f, 0.f, 0.f};

  auto stageK = [&](int kv0) {
#pragma unroll
    for (int it = 0; it < 2; it++) {
      int cidx = it * 512 + tid;
      int row = cidx >> 4, c = cidx & 15, csrc = c ^ (row & 7);
      gload16(kbase + (size_t)(kv0 + row) * 3072 + csrc * 8, &Ks[(size_t)cidx * 8]);
    }
  };
  auto stageV = [&](int kv0, int buf) {
#pragma unroll
    for (int it = 0; it < 2; it++) {
      int cidx = it * 512 + tid;
      int row = cidx >> 3, c = cidx & 7, csrc = c ^ (row & 7);
      gload16(vtb + (size_t)row * 2048 + kv0 + csrc * 8, &Vts[buf][(size_t)cidx * 8]);
    }
  };

  // Q fragments (post-RoPE), pre-scaled by log2(e)/sqrt(D)
  const bf16* qbase = qkv + (size_t)(b * 2048 + q0 + wl * 16 + lr) * 3072 + h * 128;
  bf16x8 qf[4];
#pragma unroll
  for (int kk = 0; kk < 4; kk++) {
    bf16x8 v = *(const bf16x8*)(qbase + kk * 32 + lk);
#pragma unroll
    for (int j = 0; j < 8; j++) v[j] = (bf16)((float)v[j] * SCALE2);
    qf[kk] = v;
  }

  float m_r = -1e30f, l_r = 0.f;      // per-lane scalars (q-row lr)
  f32x4 o_acc[8];
#pragma unroll
  for (int f = 0; f < 8; f++) o_acc[f] = zero4;

  stageK(0);
  stageV(0, 0);
  __syncthreads();                 // drains vmcnt(0): tile 0 resident
  int cur = 0;
  int lsrc = ((l >> 4) & 1) * 32 + (l & 15);   // lane 2*(g&1)*16 + lr

  for (int kvt = 0; kvt < nt; kvt++) {
    int kv0 = kvt * 64;
    bool act = (kvt <= qt);        // wave-uniform

    // S^T = K Q^T (swapped): sa[nj][rg] = S[q=lr][k=nj*16+g*4+rg]  (pre-scaled)
    f32x4 sa[4];
#pragma unroll
    for (int nj = 0; nj < 4; nj++) sa[nj] = zero4;
    if (act) {
#pragma unroll
      for (int kk = 0; kk < 4; kk++) {
        int cmem = (kk * 4 + g) ^ (lr & 7);
#pragma unroll
        for (int nj = 0; nj < 4; nj++) {
          bf16x8 kf = *(const bf16x8*)&Ks[(size_t)((nj * 16 + lr) * 16 + cmem) * 8];
          sa[nj] = __builtin_amdgcn_mfma_f32_16x16x32_bf16(kf, qf[kk], sa[nj], 0, 0, 0);
        }
      }
    }
    __syncthreads();               // barA: all QK reads of Ks done

    // stage next tile (K sbuf + V other dbuf half); drains at barB, covered by softmax+PV
    if (kvt + 1 < nt) {
      stageK(kv0 + 64);
      stageV(kv0 + 64, cur ^ 1);
    }

    if (act) {
      bool diag = (kvt == qt);
      int qpos = q0 + wl * 16 + lr;
      float p[4][4];
#pragma unroll
      for (int nj = 0; nj < 4; nj++)
#pragma unroll
        for (int rg = 0; rg < 4; rg++) {
          float s = sa[nj][rg];
          if (diag && (kv0 + nj * 16 + g * 4 + rg > qpos)) s = -1e30f;
          p[nj][rg] = s;
        }

      // row max (local tree + 2 shuffles)
      float a0 = fmaxf(fmaxf(p[0][0], p[0][1]), fmaxf(p[0][2], p[0][3]));
      float a1 = fmaxf(fmaxf(p[1][0], p[1][1]), fmaxf(p[1][2], p[1][3]));
      float a2 = fmaxf(fmaxf(p[2][0], p[2][1]), fmaxf(p[2][2], p[2][3]));
      float a3 = fmaxf(fmaxf(p[3][0], p[3][1]), fmaxf(p[3][2], p[3][3]));
      float mx = fmaxf(fmaxf(a0, a1), fmaxf(a2, a3));
      mx = fmaxf(mx, __shfl_xor(mx, 16));
      mx = fmaxf(mx, __shfl_xor(mx, 32));

      // defer-max (T13): rescale only when max grew past threshold (log2 domain)
      if (__any(mx > m_r + 8.0f)) {
        float mnew = fmaxf(m_r, mx);
        float sc = exp2f(m_r - mnew);
        l_r *= sc;
        m_r = mnew;
        float osc[4];
#pragma unroll
        for (int rg = 0; rg < 4; rg++) osc[rg] = __shfl(sc, g * 4 + rg);
#pragma unroll
        for (int f = 0; f < 8; f++)
#pragma unroll
          for (int rg = 0; rg < 4; rg++) o_acc[f][rg] *= osc[rg];
      }

#pragma unroll
      for (int nj = 0; nj < 4; nj++)
#pragma unroll
        for (int rg = 0; rg < 4; rg++) p[nj][rg] = exp2f(p[nj][rg] - m_r);
      float s0 = (p[0][0] + p[0][1]) + (p[0][2] + p[0][3]);
      float s1 = (p[1][0] + p[1][1]) + (p[1][2] + p[1][3]);
      float s2 = (p[2][0] + p[2][1]) + (p[2][2] + p[2][3]);
      float s3 = (p[3][0] + p[3][1]) + (p[3][2] + p[3][3]);
      float rs = (s0 + s1) + (s2 + s3);
      rs += __shfl_xor(rs, 16);
      rs += __shfl_xor(rs, 32);
      l_r += rs;

      // pack P rows to bf16 pairs (per nj: 4 bf16 = 2 dwords)
      int pwx[4], pwy[4];
#pragma unroll
      for (int nj = 0; nj < 4; nj++) {
        union { uint u; bf16 h[2]; } u0, u1;
        u0.h[0] = (bf16)p[nj][0]; u0.h[1] = (bf16)p[nj][1];
        u1.h[0] = (bf16)p[nj][2]; u1.h[1] = (bf16)p[nj][3];
        pwx[nj] = (int)u0.u; pwy[nj] = (int)u1.u;
      }

      // register-only re-fragmentation: pf(kk2) = P[lr][kk2*32+g*8 .. +7]
      bf16x8 pf0, pf1;
#pragma unroll
      for (int nj = 0; nj < 4; nj++) {
        int lo0 = __shfl(pwx[nj], lsrc);
        int lo1 = __shfl(pwy[nj], lsrc);
        int hi0 = __shfl(pwx[nj], lsrc + 16);
        int hi1 = __shfl(pwy[nj], lsrc + 16);
        if ((nj & 1) == (g >> 1)) {
          union { int i[4]; bf16x8 v; } un;
          un.i[0] = lo0; un.i[1] = lo1; un.i[2] = hi0; un.i[3] = hi1;
          if ((nj >> 1) == 0) pf0 = un.v; else pf1 = un.v;
        }
      }

      // O += P V  (V[kvt] in Vts[cur])
#pragma unroll
      for (int kk2 = 0; kk2 < 2; kk2++) {
        bf16x8 pf = kk2 == 0 ? pf0 : pf1;
        int cmem = (kk2 * 4 + g) ^ (lr & 7);
#pragma unroll
        for (int f = 0; f < 8; f++) {
          bf16x8 vf = *(const bf16x8*)&Vts[cur][(size_t)((f * 16 + lr) * 8 + cmem) * 8];
          o_acc[f] = __builtin_amdgcn_mfma_f32_16x16x32_bf16(pf, vf, o_acc[f], 0, 0, 0);
        }
      }
    }
    __syncthreads();               // barB: drains next-tile DMA; PV reads done
    cur ^= 1;
  }

  // epilogue: O / l -> ybuf; row r=g*4+rg's l lives in lane r
  float linv[4];
#pragma unroll
  for (int rg = 0; rg < 4; rg++) linv[rg] = 1.0f / __shfl(l_r, g * 4 + rg);
  size_t orow = (size_t)(b * 2048 + q0 + wl * 16);
#pragma unroll
  for (int rg = 0; rg < 4; rg++) {
    int r = g * 4 + rg;
#pragma unroll
    for (int f = 0; f < 8; f++) {
      float ov = o_acc[f][rg] * linv[rg];
      ybuf[(orow + r) * 2048 + h * 128 + f * 16 + lr] = (bf16)ov;
    }
  }
}

// ---------------- host launch ----------------
extern "C" void kernel_launch(void* const* d_in, const int* in_sizes, int n_in,
                              void* d_out, int out_size, void* d_ws, size_t ws_size,
                              hipStream_t stream) {
  const float* x  = (const float*)d_in[0];
  const float* Wq = (const float*)d_in[1];
  const float* bq = (const float*)d_in[2];
  const float* Wk = (const float*)d_in[3];
  const float* bk = (const float*)d_in[4];
  const float* Wv = (const float*)d_in[5];
  const float* bv = (const float*)d_in[6];
  const float* Wo = (const float*)d_in[7];
  const float* bo = (const float*)d_in[8];
  float* out = (float*)d_out;

  char* w = (char*)d_ws;
  auto alloc = [&](size_t bytes) { char* p = w; w += (bytes + 255) & ~(size_t)255; return p; };
  bf16*  xb    = (bf16*)alloc((size_t)4096 * 2048 * 2);
  bf16*  wqkvT = (bf16*)alloc((size_t)3072 * 2048 * 2);
  bf16*  qkv   = (bf16*)alloc((size_t)4096 * 3072 * 2);
  bf16*  vTg   = (bf16*)alloc((size_t)8 * 128 * 2048 * 2);   // [b*4+kvh][128][2048]
  float* bqkv  = (float*)alloc((size_t)3072 * 4);
  float* cost  = (float*)alloc((size_t)2048 * 64 * 4);
  float* sint  = (float*)alloc((size_t)2048 * 64 * 4);
  bf16*  ybuf  = xb;      // alias: xb dead before attn writes ybuf
  bf16*  woT   = wqkvT;   // alias: wqkvT dead before Wo transpose runs

  cvt_kernel<<<4096, 256, 0, stream>>>(x, xb, 4096 * 2048 / 8);
  concat_bias_kernel<<<12, 256, 0, stream>>>(bq, bk, bv, bqkv);
  transpose_cvt_kernel<<<dim3(32, 32), 256, 0, stream>>>(Wq, wqkvT, 2048, 2048);
  transpose_cvt_kernel<<<dim3(8, 32), 256, 0, stream>>>(Wk, wqkvT + (size_t)2048 * 2048, 2048, 512);
  transpose_cvt_kernel<<<dim3(8, 32), 256, 0, stream>>>(Wv, wqkvT + (size_t)2560 * 2048, 2048, 512);
  rope_table_kernel<<<512, 256, 0, stream>>>(cost, sint);
  gemm_bias_kernel<bf16><<<dim3(24, 32), 256, 0, stream>>>(xb, wqkvT, bqkv, qkv, 4096, 3072, 2048, 2048, 3072);
  transpose_cvt_kernel<<<dim3(32, 32), 256, 0, stream>>>(Wo, woT, 2048, 2048);
  transpose_v_kernel<<<dim3(32, 2, 8), 256, 0, stream>>>(qkv, vTg);
  rope_apply_kernel<<<5120, 256, 0, stream>>>(qkv, cost, sint);
  attn_kernel<<<dim3(16, 32), 512, 0, stream>>>(qkv, vTg, ybuf);
  gemm_bias_kernel<float><<<dim3(16, 32), 256, 0, stream>>>(ybuf, woT, bo, out, 4096, 2048, 2048, 2048, 2048);
}

// Round 18
// 291.506 us; speedup vs baseline: 1.0978x; 1.0201x over previous
//
#include <hip/hip_runtime.h>
#include <hip/hip_bf16.h>

typedef __bf16 bf16;
typedef __attribute__((ext_vector_type(8))) __bf16 bf16x8;
typedef __attribute__((ext_vector_type(4))) float f32x4;

#define SCALE2 (0.08838834764831845f * 1.4426950408889634f)  // log2(e)/sqrt(128)

__device__ inline void gload16(const bf16* g, bf16* l) {
  __builtin_amdgcn_global_load_lds((const __attribute__((address_space(1))) void*)g,
                                   (__attribute__((address_space(3))) void*)l, 16, 0, 0);
}

// ---------------- f32 -> bf16 convert (8 elems/thread) ----------------
__global__ void cvt_kernel(const float* __restrict__ in, bf16* __restrict__ out, int n8) {
  int i = blockIdx.x * 256 + threadIdx.x;
  if (i >= n8) return;
  const float* p = in + (size_t)i * 8;
  float4 a = *(const float4*)p, b = *(const float4*)(p + 4);
  union { uint4 u; bf16 h[8]; } un;
  un.h[0] = (bf16)a.x; un.h[1] = (bf16)a.y; un.h[2] = (bf16)a.z; un.h[3] = (bf16)a.w;
  un.h[4] = (bf16)b.x; un.h[5] = (bf16)b.y; un.h[6] = (bf16)b.z; un.h[7] = (bf16)b.w;
  *(uint4*)(out + (size_t)i * 8) = un.u;
}

// ---------------- bias concat (f32): [bq(2048) | bk(512) | bv(512)] ----------------
__global__ void concat_bias_kernel(const float* __restrict__ bq, const float* __restrict__ bk,
                                   const float* __restrict__ bv, float* __restrict__ o) {
  int i = blockIdx.x * 256 + threadIdx.x;
  if (i >= 3072) return;
  o[i] = (i < 2048) ? bq[i] : (i < 2560 ? bk[i - 2048] : bv[i - 2560]);
}

// ---------------- transpose+convert: in f32 [K][N] -> out bf16 [N][K] (64x64 tiles) --------
__global__ __launch_bounds__(256)
void transpose_cvt_kernel(const float* __restrict__ in, bf16* __restrict__ out, int K, int N) {
  __shared__ bf16 tile[64][72];
  int n0 = blockIdx.x * 64, k0 = blockIdx.y * 64;
  int t = threadIdx.x;
  int r8 = t >> 5, c2 = (t & 31) * 2;
#pragma unroll
  for (int it = 0; it < 8; it++) {
    int row = it * 8 + r8;
    float2 v = *(const float2*)(in + (size_t)(k0 + row) * N + n0 + c2);
    tile[row][c2] = (bf16)v.x;
    tile[row][c2 + 1] = (bf16)v.y;
  }
  __syncthreads();
  int r = t >> 3, c = (t & 7) * 8;
  int rot = t & 7;
#pragma unroll
  for (int it = 0; it < 2; it++) {
    int rr = it * 32 + r;
    union { uint4 u; bf16 h[8]; } un;
#pragma unroll
    for (int j = 0; j < 8; j++) {
      int jj = (j + rot) & 7;
      un.h[jj] = tile[c + jj][rr];   // = in[k0+c+jj][n0+rr]
    }
    *(uint4*)(out + (size_t)(n0 + rr) * K + k0 + c) = un.u;
  }
}

// ---------------- V transpose (bf16): qkv v-region [T][128] -> vT[(b*4+kvh)*128+d][2048] ----
__global__ __launch_bounds__(256)
void transpose_v_kernel(const bf16* __restrict__ qkv, bf16* __restrict__ vT) {
  __shared__ bf16 tile[64][72];
  int z = blockIdx.z;              // b*4+kvh
  int b = z >> 2, kvh = z & 3;
  int d0 = blockIdx.y * 64;        // 0 or 64
  int t0 = blockIdx.x * 64;        // 0..31 * 64
  const bf16* in = qkv + (size_t)(b * 2048) * 3072 + 2560 + kvh * 128;
  int t = threadIdx.x;
  int r = t >> 3, c = (t & 7) * 8;
#pragma unroll
  for (int it = 0; it < 2; it++) {
    int rr = it * 32 + r;          // t-row
    *(uint4*)&tile[rr][c] = *(const uint4*)(in + (size_t)(t0 + rr) * 3072 + d0 + c);
  }
  __syncthreads();
  int rot = t & 7;
#pragma unroll
  for (int it = 0; it < 2; it++) {
    int rr = it * 32 + r;          // d-row of output
    union { uint4 u; bf16 h[8]; } un;
#pragma unroll
    for (int j = 0; j < 8; j++) {
      int jj = (j + rot) & 7;
      un.h[jj] = tile[c + jj][rr]; // = in[t0+c+jj][d0+rr]
    }
    *(uint4*)(vT + (size_t)(z * 128 + d0 + rr) * 2048 + t0 + c) = un.u;
  }
}

// ---------------- RoPE tables: cos/sin [2048][64] f32 ----------------
__global__ void rope_table_kernel(float* __restrict__ cost, float* __restrict__ sint) {
  int idx = blockIdx.x * 256 + threadIdx.x;   // 2048*64
  int t = idx >> 6, i = idx & 63;
  float inv = expf(-(float)i * (logf(10000.f) / 64.f));
  float ang = (float)t * inv;
  cost[idx] = cosf(ang);
  sint[idx] = sinf(ang);
}

// ---------------- RoPE apply in-place on qkv[row][0..2560) (q then k region) ----------------
__global__ void rope_apply_kernel(bf16* __restrict__ qkv, const float* __restrict__ cost,
                                  const float* __restrict__ sint) {
  int p = blockIdx.x * 256 + threadIdx.x;     // 4096 * 320 chunks of 8 elems (4 pairs)
  if (p >= 4096 * 320) return;
  int row = p / 320;
  int rc = p - row * 320;
  int e = rc * 8;                              // element col in [0,2560)
  int t = row & 2047;
  int i0 = (e & 127) >> 1;                     // pair index within head (mult of 4)
  bf16* ptr = qkv + (size_t)row * 3072 + e;
  float4 cv = *(const float4*)(cost + t * 64 + i0);
  float4 sv = *(const float4*)(sint + t * 64 + i0);
  float c[4] = {cv.x, cv.y, cv.z, cv.w}, s[4] = {sv.x, sv.y, sv.z, sv.w};
  union { uint4 u; bf16 h[8]; } un;
  un.u = *(const uint4*)ptr;
#pragma unroll
  for (int j = 0; j < 4; j++) {
    float x0 = (float)un.h[2 * j], x1 = (float)un.h[2 * j + 1];
    un.h[2 * j]     = (bf16)(x0 * c[j] - x1 * s[j]);
    un.h[2 * j + 1] = (bf16)(x1 * c[j] + x0 * s[j]);
  }
  *(uint4*)ptr = un.u;
}

// ---------------- GEMM: C[M][ldc] = A[M][K] * Bt[N][K]^T + bias(f32) ------
// BK=32 double-buffer + both-sides chunk swizzle + bijective XCD swizzle. (round-12, kept)
template <typename OutT>
__global__ __launch_bounds__(256)
void gemm_bias_kernel(const bf16* __restrict__ A, const bf16* __restrict__ Bt,
                      const float* __restrict__ bias, OutT* __restrict__ C,
                      int M, int N, int K, int lda, int ldc) {
  __shared__ bf16 As[2][128 * 32];
  __shared__ bf16 Bs[2][128 * 32];
  int tid = threadIdx.x;
  int wv = tid >> 6, l = tid & 63;
  int wr = wv >> 1, wc = wv & 1;
  int lr = l & 15, g = l >> 4;

  int bid = blockIdx.y * gridDim.x + blockIdx.x;
  int cpx = (gridDim.x * gridDim.y) >> 3;
  int swz = (bid & 7) * cpx + (bid >> 3);
  int m0 = (swz / gridDim.x) * 128, n0 = (swz % gridDim.x) * 128;

  auto stage = [&](int k0, int buf) {
#pragma unroll
    for (int i = 0; i < 2; i++) {
      int e = i * 256 + tid;
      int row = e >> 2, c = e & 3;
      int csrc = (c ^ ((row >> 1) & 3)) * 8;
      gload16(A + (size_t)(m0 + row) * lda + k0 + csrc, &As[buf][(size_t)e * 8]);
      gload16(Bt + (size_t)(n0 + row) * K + k0 + csrc, &Bs[buf][(size_t)e * 8]);
    }
  };

  f32x4 acc[4][4] = {};
  stage(0, 0);
  __syncthreads();
  int cur = 0;
  int cswz = (g ^ ((lr >> 1) & 3)) * 8;
  for (int k0 = 32; k0 <= K; k0 += 32) {
    if (k0 < K) stage(k0, cur ^ 1);
    bf16x8 a[4], b[4];
#pragma unroll
    for (int mi = 0; mi < 4; mi++)
      a[mi] = *(const bf16x8*)&As[cur][(size_t)(wr * 64 + mi * 16 + lr) * 32 + cswz];
#pragma unroll
    for (int nj = 0; nj < 4; nj++)
      b[nj] = *(const bf16x8*)&Bs[cur][(size_t)(wc * 64 + nj * 16 + lr) * 32 + cswz];
#pragma unroll
    for (int mi = 0; mi < 4; mi++)
#pragma unroll
      for (int nj = 0; nj < 4; nj++)
        acc[mi][nj] = __builtin_amdgcn_mfma_f32_16x16x32_bf16(a[mi], b[nj], acc[mi][nj], 0, 0, 0);
    __syncthreads();
    cur ^= 1;
  }
#pragma unroll
  for (int nj = 0; nj < 4; nj++) {
    int gc = n0 + wc * 64 + nj * 16 + lr;
    float bv = bias[gc];
#pragma unroll
    for (int mi = 0; mi < 4; mi++) {
      int gr = m0 + wr * 64 + mi * 16 + g * 4;
#pragma unroll
      for (int reg = 0; reg < 4; reg++)
        C[(size_t)(gr + reg) * ldc + gc] = (OutT)(acc[mi][nj][reg] + bv);
    }
  }
}

// ---- Flash attention (causal, GQA): r13 structure (best measured) + pre-scaled Q + T5
//      setprio around MFMA clusters. 8-wave piggyback {31-p, p}, K single-buf + V^T dbuf
//      both staged post-barA (covered by softmax+PV), Ps LDS re-frag, defer-max. ----
__global__ __launch_bounds__(512, 4)
void attn_kernel(const bf16* __restrict__ qkv, const bf16* __restrict__ vT,
                 bf16* __restrict__ ybuf) {
  __shared__ bf16 Ks[64 * 128];       // K single-buf [kpos][d], chunk-swizzled c^=(row&7)
  __shared__ bf16 Vts[2][128 * 64];   // V^T dbuf [d][s], chunk-swizzled c^=(row&7)
  __shared__ bf16 Ps[8][16][72];      // per-wave P tile [q-row][k], padded

  int pair = blockIdx.x;          // 0..15
  int bh = blockIdx.y;            // 0..31
  int b = bh >> 4, h = bh & 15;
  int kvh = h >> 2;               // G=4
  int tid = threadIdx.x, w = tid >> 6, l = tid & 63;
  int lr = l & 15, g = l >> 4, lk = g * 8;
  int wl = w & 3, wg = w >> 2;
  int qt = wg ? pair : 31 - pair;       // group 0 -> long tile
  int q0 = qt * 64;
  int nt = 32 - pair;                   // iterations (max over both groups)

  const bf16* kbase = qkv + (size_t)(b * 2048) * 3072 + 2048 + kvh * 128;
  const bf16* vtb   = vT + (size_t)(b * 4 + kvh) * 128 * 2048;
  f32x4 zero4 = {0.f, 0.f, 0.f, 0.f};

  auto stageK = [&](int kv0) {
#pragma unroll
    for (int it = 0; it < 2; it++) {
      int cidx = it * 512 + tid;
      int row = cidx >> 4, c = cidx & 15, csrc = c ^ (row & 7);
      gload16(kbase + (size_t)(kv0 + row) * 3072 + csrc * 8, &Ks[(size_t)cidx * 8]);
    }
  };
  auto stageV = [&](int kv0, int buf) {
#pragma unroll
    for (int it = 0; it < 2; it++) {
      int cidx = it * 512 + tid;
      int row = cidx >> 3, c = cidx & 7, csrc = c ^ (row & 7);
      gload16(vtb + (size_t)row * 2048 + kv0 + csrc * 8, &Vts[buf][(size_t)cidx * 8]);
    }
  };

  // Q fragments (post-RoPE), pre-scaled by log2(e)/sqrt(D)
  const bf16* qbase = qkv + (size_t)(b * 2048 + q0 + wl * 16 + lr) * 3072 + h * 128;
  bf16x8 qf[4];
#pragma unroll
  for (int kk = 0; kk < 4; kk++) {
    bf16x8 v = *(const bf16x8*)(qbase + kk * 32 + lk);
#pragma unroll
    for (int j = 0; j < 8; j++) v[j] = (bf16)((float)v[j] * SCALE2);
    qf[kk] = v;
  }

  float m_r = -1e30f, l_r = 0.f;      // per-lane scalars (q-row lr)
  f32x4 o_acc[8];
#pragma unroll
  for (int f = 0; f < 8; f++) o_acc[f] = zero4;

  stageK(0);
  stageV(0, 0);
  __syncthreads();                 // drains vmcnt(0): tile 0 resident
  int cur = 0;

  for (int kvt = 0; kvt < nt; kvt++) {
    int kv0 = kvt * 64;
    bool act = (kvt <= qt);        // wave-uniform

    // S^T = K Q^T (swapped): sa[nj][rg] = S[q=lr][k=nj*16+g*4+rg]  (pre-scaled)
    f32x4 sa[4];
#pragma unroll
    for (int nj = 0; nj < 4; nj++) sa[nj] = zero4;
    if (act) {
      __builtin_amdgcn_s_setprio(1);
#pragma unroll
      for (int kk = 0; kk < 4; kk++) {
        int cmem = (kk * 4 + g) ^ (lr & 7);
#pragma unroll
        for (int nj = 0; nj < 4; nj++) {
          bf16x8 kf = *(const bf16x8*)&Ks[(size_t)((nj * 16 + lr) * 16 + cmem) * 8];
          sa[nj] = __builtin_amdgcn_mfma_f32_16x16x32_bf16(kf, qf[kk], sa[nj], 0, 0, 0);
        }
      }
      __builtin_amdgcn_s_setprio(0);
    }
    __syncthreads();               // barA: all QK reads of Ks done

    // stage next tile (K sbuf now safe; V into other dbuf half); drains at barB,
    // covered by softmax+PV below.
    if (kvt + 1 < nt) {
      stageK(kv0 + 64);
      stageV(kv0 + 64, cur ^ 1);
    }

    if (act) {
      bool diag = (kvt == qt);
      int qpos = q0 + wl * 16 + lr;
      float p[4][4];
#pragma unroll
      for (int nj = 0; nj < 4; nj++)
#pragma unroll
        for (int rg = 0; rg < 4; rg++) {
          float s = sa[nj][rg];
          if (diag && (kv0 + nj * 16 + g * 4 + rg > qpos)) s = -1e30f;
          p[nj][rg] = s;
        }

      // row max (local tree + 2 shuffles)
      float a0 = fmaxf(fmaxf(p[0][0], p[0][1]), fmaxf(p[0][2], p[0][3]));
      float a1 = fmaxf(fmaxf(p[1][0], p[1][1]), fmaxf(p[1][2], p[1][3]));
      float a2 = fmaxf(fmaxf(p[2][0], p[2][1]), fmaxf(p[2][2], p[2][3]));
      float a3 = fmaxf(fmaxf(p[3][0], p[3][1]), fmaxf(p[3][2], p[3][3]));
      float mx = fmaxf(fmaxf(a0, a1), fmaxf(a2, a3));
      mx = fmaxf(mx, __shfl_xor(mx, 16));
      mx = fmaxf(mx, __shfl_xor(mx, 32));

      // defer-max (T13): rescale only when max grew past threshold (log2 domain)
      if (__any(mx > m_r + 8.0f)) {
        float mnew = fmaxf(m_r, mx);
        float sc = exp2f(m_r - mnew);
        l_r *= sc;
        m_r = mnew;
        float osc[4];
#pragma unroll
        for (int rg = 0; rg < 4; rg++) osc[rg] = __shfl(sc, g * 4 + rg);
#pragma unroll
        for (int f = 0; f < 8; f++)
#pragma unroll
          for (int rg = 0; rg < 4; rg++) o_acc[f][rg] *= osc[rg];
      }

#pragma unroll
      for (int nj = 0; nj < 4; nj++)
#pragma unroll
        for (int rg = 0; rg < 4; rg++) p[nj][rg] = exp2f(p[nj][rg] - m_r);
      float s0 = (p[0][0] + p[0][1]) + (p[0][2] + p[0][3]);
      float s1 = (p[1][0] + p[1][1]) + (p[1][2] + p[1][3]);
      float s2 = (p[2][0] + p[2][1]) + (p[2][2] + p[2][3]);
      float s3 = (p[3][0] + p[3][1]) + (p[3][2] + p[3][3]);
      float rs = (s0 + s1) + (s2 + s3);
      rs += __shfl_xor(rs, 16);
      rs += __shfl_xor(rs, 32);
      l_r += rs;

      // P -> LDS (b64 writes)
#pragma unroll
      for (int nj = 0; nj < 4; nj++) {
        union { uint2 u; bf16 hh[4]; } pw;
#pragma unroll
        for (int rg = 0; rg < 4; rg++) pw.hh[rg] = (bf16)p[nj][rg];
        *(uint2*)&Ps[w][lr][nj * 16 + g * 4] = pw.u;
      }
      asm volatile("s_waitcnt lgkmcnt(0)" ::: "memory");
      __builtin_amdgcn_sched_barrier(0);

      // O += P V  (V[kvt] in Vts[cur])
      __builtin_amdgcn_s_setprio(1);
#pragma unroll
      for (int kk2 = 0; kk2 < 2; kk2++) {
        bf16x8 pf = *(const bf16x8*)&Ps[w][lr][kk2 * 32 + lk];
        int cmem = (kk2 * 4 + g) ^ (lr & 7);
#pragma unroll
        for (int f = 0; f < 8; f++) {
          bf16x8 vf = *(const bf16x8*)&Vts[cur][(size_t)((f * 16 + lr) * 8 + cmem) * 8];
          o_acc[f] = __builtin_amdgcn_mfma_f32_16x16x32_bf16(pf, vf, o_acc[f], 0, 0, 0);
        }
      }
      __builtin_amdgcn_s_setprio(0);
    }
    __syncthreads();               // barB: drains next-tile DMA; PV reads done
    cur ^= 1;
  }

  // epilogue: O / l -> ybuf; row r=g*4+rg's l lives in lane r
  float linv[4];
#pragma unroll
  for (int rg = 0; rg < 4; rg++) linv[rg] = 1.0f / __shfl(l_r, g * 4 + rg);
  size_t orow = (size_t)(b * 2048 + q0 + wl * 16);
#pragma unroll
  for (int rg = 0; rg < 4; rg++) {
    int r = g * 4 + rg;
#pragma unroll
    for (int f = 0; f < 8; f++) {
      float ov = o_acc[f][rg] * linv[rg];
      ybuf[(orow + r) * 2048 + h * 128 + f * 16 + lr] = (bf16)ov;
    }
  }
}

// ---------------- host launch ----------------
extern "C" void kernel_launch(void* const* d_in, const int* in_sizes, int n_in,
                              void* d_out, int out_size, void* d_ws, size_t ws_size,
                              hipStream_t stream) {
  const float* x  = (const float*)d_in[0];
  const float* Wq = (const float*)d_in[1];
  const float* bq = (const float*)d_in[2];
  const float* Wk = (const float*)d_in[3];
  const float* bk = (const float*)d_in[4];
  const float* Wv = (const float*)d_in[5];
  const float* bv = (const float*)d_in[6];
  const float* Wo = (const float*)d_in[7];
  const float* bo = (const float*)d_in[8];
  float* out = (float*)d_out;

  char* w = (char*)d_ws;
  auto alloc = [&](size_t bytes) { char* p = w; w += (bytes + 255) & ~(size_t)255; return p; };
  bf16*  xb    = (bf16*)alloc((size_t)4096 * 2048 * 2);
  bf16*  wqkvT = (bf16*)alloc((size_t)3072 * 2048 * 2);
  bf16*  qkv   = (bf16*)alloc((size_t)4096 * 3072 * 2);
  bf16*  vTg   = (bf16*)alloc((size_t)8 * 128 * 2048 * 2);   // [b*4+kvh][128][2048]
  float* bqkv  = (float*)alloc((size_t)3072 * 4);
  float* cost  = (float*)alloc((size_t)2048 * 64 * 4);
  float* sint  = (float*)alloc((size_t)2048 * 64 * 4);
  bf16*  ybuf  = xb;      // alias: xb dead before attn writes ybuf
  bf16*  woT   = wqkvT;   // alias: wqkvT dead before Wo transpose runs

  cvt_kernel<<<4096, 256, 0, stream>>>(x, xb, 4096 * 2048 / 8);
  concat_bias_kernel<<<12, 256, 0, stream>>>(bq, bk, bv, bqkv);
  transpose_cvt_kernel<<<dim3(32, 32), 256, 0, stream>>>(Wq, wqkvT, 2048, 2048);
  transpose_cvt_kernel<<<dim3(8, 32), 256, 0, stream>>>(Wk, wqkvT + (size_t)2048 * 2048, 2048, 512);
  transpose_cvt_kernel<<<dim3(8, 32), 256, 0, stream>>>(Wv, wqkvT + (size_t)2560 * 2048, 2048, 512);
  rope_table_kernel<<<512, 256, 0, stream>>>(cost, sint);
  gemm_bias_kernel<bf16><<<dim3(24, 32), 256, 0, stream>>>(xb, wqkvT, bqkv, qkv, 4096, 3072, 2048, 2048, 3072);
  transpose_cvt_kernel<<<dim3(32, 32), 256, 0, stream>>>(Wo, woT, 2048, 2048);
  transpose_v_kernel<<<dim3(32, 2, 8), 256, 0, stream>>>(qkv, vTg);
  rope_apply_kernel<<<5120, 256, 0, stream>>>(qkv, cost, sint);
  attn_kernel<<<dim3(16, 32), 512, 0, stream>>>(qkv, vTg, ybuf);
  gemm_bias_kernel<float><<<dim3(16, 32), 256, 0, stream>>>(ybuf, woT, bo, out, 4096, 2048, 2048, 2048, 2048);
}

// Round 19
// 255.602 us; speedup vs baseline: 1.2520x; 1.1405x over previous
//
#include <hip/hip_runtime.h>
#include <hip/hip_bf16.h>

typedef __bf16 bf16;
typedef __attribute__((ext_vector_type(8))) __bf16 bf16x8;
typedef __attribute__((ext_vector_type(4))) float f32x4;

#define SCALE2 (0.08838834764831845f * 1.4426950408889634f)  // log2(e)/sqrt(128)

__device__ inline void gload16(const bf16* g, bf16* l) {
  __builtin_amdgcn_global_load_lds((const __attribute__((address_space(1))) void*)g,
                                   (__attribute__((address_space(3))) void*)l, 16, 0, 0);
}

// ---- prep: blocks [0,4096) cvt x->bf16; blocks [4096,4608) rope tables (+bias concat) ----
__global__ __launch_bounds__(256)
void prep_kernel(const float* __restrict__ x, bf16* __restrict__ xb,
                 const float* __restrict__ bq, const float* __restrict__ bk,
                 const float* __restrict__ bv, float* __restrict__ bqkv,
                 float* __restrict__ cost, float* __restrict__ sint) {
  int bid = blockIdx.x;
  if (bid < 4096) {
    int i = bid * 256 + threadIdx.x;           // 4096*256 = n8 exactly
    const float* p = x + (size_t)i * 8;
    float4 a = *(const float4*)p, b = *(const float4*)(p + 4);
    union { uint4 u; bf16 h[8]; } un;
    un.h[0] = (bf16)a.x; un.h[1] = (bf16)a.y; un.h[2] = (bf16)a.z; un.h[3] = (bf16)a.w;
    un.h[4] = (bf16)b.x; un.h[5] = (bf16)b.y; un.h[6] = (bf16)b.z; un.h[7] = (bf16)b.w;
    *(uint4*)(xb + (size_t)i * 8) = un.u;
  } else {
    int idx = (bid - 4096) * 256 + threadIdx.x;   // 0..131071 = 2048*64
    int t = idx >> 6, i = idx & 63;
    float inv = expf(-(float)i * (logf(10000.f) / 64.f));
    float ang = (float)t * inv;
    cost[idx] = cosf(ang);
    sint[idx] = sinf(ang);
    if (idx < 3072)
      bqkv[idx] = (idx < 2048) ? bq[idx] : (idx < 2560 ? bk[idx - 2048] : bv[idx - 2560]);
  }
}

// ---- fused W_{q,k,v} transpose+convert: bx<32 Wq, <40 Wk, else Wv ----
__global__ __launch_bounds__(256)
void transpose_qkv_cvt_kernel(const float* __restrict__ Wq, const float* __restrict__ Wk,
                              const float* __restrict__ Wv, bf16* __restrict__ wqkvT) {
  __shared__ bf16 tile[64][72];
  int bx = blockIdx.x;
  const float* in; bf16* out; int N, n0;
  const int K = 2048;
  if (bx < 32)      { in = Wq; out = wqkvT;                          N = 2048; n0 = bx * 64; }
  else if (bx < 40) { in = Wk; out = wqkvT + (size_t)2048 * 2048;   N = 512;  n0 = (bx - 32) * 64; }
  else              { in = Wv; out = wqkvT + (size_t)2560 * 2048;   N = 512;  n0 = (bx - 40) * 64; }
  int k0 = blockIdx.y * 64;
  int t = threadIdx.x;
  int r8 = t >> 5, c2 = (t & 31) * 2;
#pragma unroll
  for (int it = 0; it < 8; it++) {
    int row = it * 8 + r8;
    float2 v = *(const float2*)(in + (size_t)(k0 + row) * N + n0 + c2);
    tile[row][c2] = (bf16)v.x;
    tile[row][c2 + 1] = (bf16)v.y;
  }
  __syncthreads();
  int r = t >> 3, c = (t & 7) * 8;
  int rot = t & 7;
#pragma unroll
  for (int it = 0; it < 2; it++) {
    int rr = it * 32 + r;
    union { uint4 u; bf16 h[8]; } un;
#pragma unroll
    for (int j = 0; j < 8; j++) {
      int jj = (j + rot) & 7;
      un.h[jj] = tile[c + jj][rr];   // = in[k0+c+jj][n0+rr]
    }
    *(uint4*)(out + (size_t)(n0 + rr) * K + k0 + c) = un.u;
  }
}

// ---------------- transpose+convert (Wo only; runs after gemm1, woT aliases wqkvT) -------
__global__ __launch_bounds__(256)
void transpose_cvt_kernel(const float* __restrict__ in, bf16* __restrict__ out, int K, int N) {
  __shared__ bf16 tile[64][72];
  int n0 = blockIdx.x * 64, k0 = blockIdx.y * 64;
  int t = threadIdx.x;
  int r8 = t >> 5, c2 = (t & 31) * 2;
#pragma unroll
  for (int it = 0; it < 8; it++) {
    int row = it * 8 + r8;
    float2 v = *(const float2*)(in + (size_t)(k0 + row) * N + n0 + c2);
    tile[row][c2] = (bf16)v.x;
    tile[row][c2 + 1] = (bf16)v.y;
  }
  __syncthreads();
  int r = t >> 3, c = (t & 7) * 8;
  int rot = t & 7;
#pragma unroll
  for (int it = 0; it < 2; it++) {
    int rr = it * 32 + r;
    union { uint4 u; bf16 h[8]; } un;
#pragma unroll
    for (int j = 0; j < 8; j++) {
      int jj = (j + rot) & 7;
      un.h[jj] = tile[c + jj][rr];
    }
    *(uint4*)(out + (size_t)(n0 + rr) * K + k0 + c) = un.u;
  }
}

// ---- fused RoPE-apply (blocks <5120) + V transpose (blocks 5120..5631) ----
// Disjoint qkv regions: rope RWs cols [0,2560); transpose_v reads cols [2560,3072).
__global__ __launch_bounds__(256)
void ropev_kernel(bf16* __restrict__ qkv, const float* __restrict__ cost,
                  const float* __restrict__ sint, bf16* __restrict__ vT) {
  __shared__ bf16 tile[64][72];
  if (blockIdx.x < 5120) {
    int p = blockIdx.x * 256 + threadIdx.x;     // 4096*320 chunks of 8 elems
    if (p >= 4096 * 320) return;
    int row = p / 320;
    int rc = p - row * 320;
    int e = rc * 8;
    int t = row & 2047;
    int i0 = (e & 127) >> 1;
    bf16* ptr = qkv + (size_t)row * 3072 + e;
    float4 cv = *(const float4*)(cost + t * 64 + i0);
    float4 sv = *(const float4*)(sint + t * 64 + i0);
    float c[4] = {cv.x, cv.y, cv.z, cv.w}, s[4] = {sv.x, sv.y, sv.z, sv.w};
    union { uint4 u; bf16 h[8]; } un;
    un.u = *(const uint4*)ptr;
#pragma unroll
    for (int j = 0; j < 4; j++) {
      float x0 = (float)un.h[2 * j], x1 = (float)un.h[2 * j + 1];
      un.h[2 * j]     = (bf16)(x0 * c[j] - x1 * s[j]);
      un.h[2 * j + 1] = (bf16)(x1 * c[j] + x0 * s[j]);
    }
    *(uint4*)ptr = un.u;
  } else {
    int bid = blockIdx.x - 5120;     // 0..511
    int z = bid & 7;                 // b*4+kvh
    int yy = (bid >> 3) & 1;
    int xx = bid >> 4;               // 0..31
    int b = z >> 2, kvh = z & 3;
    int d0 = yy * 64;
    int t0 = xx * 64;
    const bf16* in = qkv + (size_t)(b * 2048) * 3072 + 2560 + kvh * 128;
    int t = threadIdx.x;
    int r = t >> 3, c = (t & 7) * 8;
#pragma unroll
    for (int it = 0; it < 2; it++) {
      int rr = it * 32 + r;
      *(uint4*)&tile[rr][c] = *(const uint4*)(in + (size_t)(t0 + rr) * 3072 + d0 + c);
    }
    __syncthreads();
    int rot = t & 7;
#pragma unroll
    for (int it = 0; it < 2; it++) {
      int rr = it * 32 + r;
      union { uint4 u; bf16 h[8]; } un;
#pragma unroll
      for (int j = 0; j < 8; j++) {
        int jj = (j + rot) & 7;
        un.h[jj] = tile[c + jj][rr];
      }
      *(uint4*)(vT + (size_t)(z * 128 + d0 + rr) * 2048 + t0 + c) = un.u;
    }
  }
}

// ---------------- GEMM: BK=32 dbuf + both-sides chunk swizzle + XCD swizzle (r12) ------
template <typename OutT>
__global__ __launch_bounds__(256)
void gemm_bias_kernel(const bf16* __restrict__ A, const bf16* __restrict__ Bt,
                      const float* __restrict__ bias, OutT* __restrict__ C,
                      int M, int N, int K, int lda, int ldc) {
  __shared__ bf16 As[2][128 * 32];
  __shared__ bf16 Bs[2][128 * 32];
  int tid = threadIdx.x;
  int wv = tid >> 6, l = tid & 63;
  int wr = wv >> 1, wc = wv & 1;
  int lr = l & 15, g = l >> 4;

  int bid = blockIdx.y * gridDim.x + blockIdx.x;
  int cpx = (gridDim.x * gridDim.y) >> 3;
  int swz = (bid & 7) * cpx + (bid >> 3);
  int m0 = (swz / gridDim.x) * 128, n0 = (swz % gridDim.x) * 128;

  auto stage = [&](int k0, int buf) {
#pragma unroll
    for (int i = 0; i < 2; i++) {
      int e = i * 256 + tid;
      int row = e >> 2, c = e & 3;
      int csrc = (c ^ ((row >> 1) & 3)) * 8;
      gload16(A + (size_t)(m0 + row) * lda + k0 + csrc, &As[buf][(size_t)e * 8]);
      gload16(Bt + (size_t)(n0 + row) * K + k0 + csrc, &Bs[buf][(size_t)e * 8]);
    }
  };

  f32x4 acc[4][4] = {};
  stage(0, 0);
  __syncthreads();
  int cur = 0;
  int cswz = (g ^ ((lr >> 1) & 3)) * 8;
  for (int k0 = 32; k0 <= K; k0 += 32) {
    if (k0 < K) stage(k0, cur ^ 1);
    bf16x8 a[4], b[4];
#pragma unroll
    for (int mi = 0; mi < 4; mi++)
      a[mi] = *(const bf16x8*)&As[cur][(size_t)(wr * 64 + mi * 16 + lr) * 32 + cswz];
#pragma unroll
    for (int nj = 0; nj < 4; nj++)
      b[nj] = *(const bf16x8*)&Bs[cur][(size_t)(wc * 64 + nj * 16 + lr) * 32 + cswz];
#pragma unroll
    for (int mi = 0; mi < 4; mi++)
#pragma unroll
      for (int nj = 0; nj < 4; nj++)
        acc[mi][nj] = __builtin_amdgcn_mfma_f32_16x16x32_bf16(a[mi], b[nj], acc[mi][nj], 0, 0, 0);
    __syncthreads();
    cur ^= 1;
  }
#pragma unroll
  for (int nj = 0; nj < 4; nj++) {
    int gc = n0 + wc * 64 + nj * 16 + lr;
    float bv = bias[gc];
#pragma unroll
    for (int mi = 0; mi < 4; mi++) {
      int gr = m0 + wr * 64 + mi * 16 + g * 4;
#pragma unroll
      for (int reg = 0; reg < 4; reg++)
        C[(size_t)(gr + reg) * ldc + gc] = (OutT)(acc[mi][nj][reg] + bv);
    }
  }
}

// ---- Flash attention (causal, GQA): r13 structure + pre-scaled Q + setprio (r18) ----
__global__ __launch_bounds__(512, 4)
void attn_kernel(const bf16* __restrict__ qkv, const bf16* __restrict__ vT,
                 bf16* __restrict__ ybuf) {
  __shared__ bf16 Ks[64 * 128];       // K single-buf [kpos][d], chunk-swizzled c^=(row&7)
  __shared__ bf16 Vts[2][128 * 64];   // V^T dbuf [d][s], chunk-swizzled c^=(row&7)
  __shared__ bf16 Ps[8][16][72];      // per-wave P tile [q-row][k], padded

  int pair = blockIdx.x;          // 0..15
  int bh = blockIdx.y;            // 0..31
  int b = bh >> 4, h = bh & 15;
  int kvh = h >> 2;               // G=4
  int tid = threadIdx.x, w = tid >> 6, l = tid & 63;
  int lr = l & 15, g = l >> 4, lk = g * 8;
  int wl = w & 3, wg = w >> 2;
  int qt = wg ? pair : 31 - pair;       // group 0 -> long tile
  int q0 = qt * 64;
  int nt = 32 - pair;                   // iterations (max over both groups)

  const bf16* kbase = qkv + (size_t)(b * 2048) * 3072 + 2048 + kvh * 128;
  const bf16* vtb   = vT + (size_t)(b * 4 + kvh) * 128 * 2048;
  f32x4 zero4 = {0.f, 0.f, 0.f, 0.f};

  auto stageK = [&](int kv0) {
#pragma unroll
    for (int it = 0; it < 2; it++) {
      int cidx = it * 512 + tid;
      int row = cidx >> 4, c = cidx & 15, csrc = c ^ (row & 7);
      gload16(kbase + (size_t)(kv0 + row) * 3072 + csrc * 8, &Ks[(size_t)cidx * 8]);
    }
  };
  auto stageV = [&](int kv0, int buf) {
#pragma unroll
    for (int it = 0; it < 2; it++) {
      int cidx = it * 512 + tid;
      int row = cidx >> 3, c = cidx & 7, csrc = c ^ (row & 7);
      gload16(vtb + (size_t)row * 2048 + kv0 + csrc * 8, &Vts[buf][(size_t)cidx * 8]);
    }
  };

  // Q fragments (post-RoPE), pre-scaled by log2(e)/sqrt(D)
  const bf16* qbase = qkv + (size_t)(b * 2048 + q0 + wl * 16 + lr) * 3072 + h * 128;
  bf16x8 qf[4];
#pragma unroll
  for (int kk = 0; kk < 4; kk++) {
    bf16x8 v = *(const bf16x8*)(qbase + kk * 32 + lk);
#pragma unroll
    for (int j = 0; j < 8; j++) v[j] = (bf16)((float)v[j] * SCALE2);
    qf[kk] = v;
  }

  float m_r = -1e30f, l_r = 0.f;      // per-lane scalars (q-row lr)
  f32x4 o_acc[8];
#pragma unroll
  for (int f = 0; f < 8; f++) o_acc[f] = zero4;

  stageK(0);
  stageV(0, 0);
  __syncthreads();                 // drains vmcnt(0): tile 0 resident
  int cur = 0;

  for (int kvt = 0; kvt < nt; kvt++) {
    int kv0 = kvt * 64;
    bool act = (kvt <= qt);        // wave-uniform

    f32x4 sa[4];
#pragma unroll
    for (int nj = 0; nj < 4; nj++) sa[nj] = zero4;
    if (act) {
      __builtin_amdgcn_s_setprio(1);
#pragma unroll
      for (int kk = 0; kk < 4; kk++) {
        int cmem = (kk * 4 + g) ^ (lr & 7);
#pragma unroll
        for (int nj = 0; nj < 4; nj++) {
          bf16x8 kf = *(const bf16x8*)&Ks[(size_t)((nj * 16 + lr) * 16 + cmem) * 8];
          sa[nj] = __builtin_amdgcn_mfma_f32_16x16x32_bf16(kf, qf[kk], sa[nj], 0, 0, 0);
        }
      }
      __builtin_amdgcn_s_setprio(0);
    }
    __syncthreads();               // barA: all QK reads of Ks done

    if (kvt + 1 < nt) {
      stageK(kv0 + 64);
      stageV(kv0 + 64, cur ^ 1);
    }

    if (act) {
      bool diag = (kvt == qt);
      int qpos = q0 + wl * 16 + lr;
      float p[4][4];
#pragma unroll
      for (int nj = 0; nj < 4; nj++)
#pragma unroll
        for (int rg = 0; rg < 4; rg++) {
          float s = sa[nj][rg];
          if (diag && (kv0 + nj * 16 + g * 4 + rg > qpos)) s = -1e30f;
          p[nj][rg] = s;
        }

      float a0 = fmaxf(fmaxf(p[0][0], p[0][1]), fmaxf(p[0][2], p[0][3]));
      float a1 = fmaxf(fmaxf(p[1][0], p[1][1]), fmaxf(p[1][2], p[1][3]));
      float a2 = fmaxf(fmaxf(p[2][0], p[2][1]), fmaxf(p[2][2], p[2][3]));
      float a3 = fmaxf(fmaxf(p[3][0], p[3][1]), fmaxf(p[3][2], p[3][3]));
      float mx = fmaxf(fmaxf(a0, a1), fmaxf(a2, a3));
      mx = fmaxf(mx, __shfl_xor(mx, 16));
      mx = fmaxf(mx, __shfl_xor(mx, 32));

      if (__any(mx > m_r + 8.0f)) {
        float mnew = fmaxf(m_r, mx);
        float sc = exp2f(m_r - mnew);
        l_r *= sc;
        m_r = mnew;
        float osc[4];
#pragma unroll
        for (int rg = 0; rg < 4; rg++) osc[rg] = __shfl(sc, g * 4 + rg);
#pragma unroll
        for (int f = 0; f < 8; f++)
#pragma unroll
          for (int rg = 0; rg < 4; rg++) o_acc[f][rg] *= osc[rg];
      }

#pragma unroll
      for (int nj = 0; nj < 4; nj++)
#pragma unroll
        for (int rg = 0; rg < 4; rg++) p[nj][rg] = exp2f(p[nj][rg] - m_r);
      float s0 = (p[0][0] + p[0][1]) + (p[0][2] + p[0][3]);
      float s1 = (p[1][0] + p[1][1]) + (p[1][2] + p[1][3]);
      float s2 = (p[2][0] + p[2][1]) + (p[2][2] + p[2][3]);
      float s3 = (p[3][0] + p[3][1]) + (p[3][2] + p[3][3]);
      float rs = (s0 + s1) + (s2 + s3);
      rs += __shfl_xor(rs, 16);
      rs += __shfl_xor(rs, 32);
      l_r += rs;

#pragma unroll
      for (int nj = 0; nj < 4; nj++) {
        union { uint2 u; bf16 hh[4]; } pw;
#pragma unroll
        for (int rg = 0; rg < 4; rg++) pw.hh[rg] = (bf16)p[nj][rg];
        *(uint2*)&Ps[w][lr][nj * 16 + g * 4] = pw.u;
      }
      asm volatile("s_waitcnt lgkmcnt(0)" ::: "memory");
      __builtin_amdgcn_sched_barrier(0);

      __builtin_amdgcn_s_setprio(1);
#pragma unroll
      for (int kk2 = 0; kk2 < 2; kk2++) {
        bf16x8 pf = *(const bf16x8*)&Ps[w][lr][kk2 * 32 + lk];
        int cmem = (kk2 * 4 + g) ^ (lr & 7);
#pragma unroll
        for (int f = 0; f < 8; f++) {
          bf16x8 vf = *(const bf16x8*)&Vts[cur][(size_t)((f * 16 + lr) * 8 + cmem) * 8];
          o_acc[f] = __builtin_amdgcn_mfma_f32_16x16x32_bf16(pf, vf, o_acc[f], 0, 0, 0);
        }
      }
      __builtin_amdgcn_s_setprio(0);
    }
    __syncthreads();               // barB: drains next-tile DMA; PV reads done
    cur ^= 1;
  }

  float linv[4];
#pragma unroll
  for (int rg = 0; rg < 4; rg++) linv[rg] = 1.0f / __shfl(l_r, g * 4 + rg);
  size_t orow = (size_t)(b * 2048 + q0 + wl * 16);
#pragma unroll
  for (int rg = 0; rg < 4; rg++) {
    int r = g * 4 + rg;
#pragma unroll
    for (int f = 0; f < 8; f++) {
      float ov = o_acc[f][rg] * linv[rg];
      ybuf[(orow + r) * 2048 + h * 128 + f * 16 + lr] = (bf16)ov;
    }
  }
}

// ---------------- host launch: 7 dispatches (was 11) ----------------
extern "C" void kernel_launch(void* const* d_in, const int* in_sizes, int n_in,
                              void* d_out, int out_size, void* d_ws, size_t ws_size,
                              hipStream_t stream) {
  const float* x  = (const float*)d_in[0];
  const float* Wq = (const float*)d_in[1];
  const float* bq = (const float*)d_in[2];
  const float* Wk = (const float*)d_in[3];
  const float* bk = (const float*)d_in[4];
  const float* Wv = (const float*)d_in[5];
  const float* bv = (const float*)d_in[6];
  const float* Wo = (const float*)d_in[7];
  const float* bo = (const float*)d_in[8];
  float* out = (float*)d_out;

  char* w = (char*)d_ws;
  auto alloc = [&](size_t bytes) { char* p = w; w += (bytes + 255) & ~(size_t)255; return p; };
  bf16*  xb    = (bf16*)alloc((size_t)4096 * 2048 * 2);
  bf16*  wqkvT = (bf16*)alloc((size_t)3072 * 2048 * 2);
  bf16*  qkv   = (bf16*)alloc((size_t)4096 * 3072 * 2);
  bf16*  vTg   = (bf16*)alloc((size_t)8 * 128 * 2048 * 2);   // [b*4+kvh][128][2048]
  float* bqkv  = (float*)alloc((size_t)3072 * 4);
  float* cost  = (float*)alloc((size_t)2048 * 64 * 4);
  float* sint  = (float*)alloc((size_t)2048 * 64 * 4);
  bf16*  ybuf  = xb;      // alias: xb dead before attn writes ybuf
  bf16*  woT   = wqkvT;   // alias: wqkvT dead before Wo transpose runs

  prep_kernel<<<4608, 256, 0, stream>>>(x, xb, bq, bk, bv, bqkv, cost, sint);
  transpose_qkv_cvt_kernel<<<dim3(48, 32), 256, 0, stream>>>(Wq, Wk, Wv, wqkvT);
  gemm_bias_kernel<bf16><<<dim3(24, 32), 256, 0, stream>>>(xb, wqkvT, bqkv, qkv, 4096, 3072, 2048, 2048, 3072);
  transpose_cvt_kernel<<<dim3(32, 32), 256, 0, stream>>>(Wo, woT, 2048, 2048);
  ropev_kernel<<<5632, 256, 0, stream>>>(qkv, cost, sint, vTg);
  attn_kernel<<<dim3(16, 32), 512, 0, stream>>>(qkv, vTg, ybuf);
  gemm_bias_kernel<float><<<dim3(16, 32), 256, 0, stream>>>(ybuf, woT, bo, out, 4096, 2048, 2048, 2048, 2048);
}

// Round 20
// 235.759 us; speedup vs baseline: 1.3574x; 1.0842x over previous
//
#include <hip/hip_runtime.h>
#include <hip/hip_bf16.h>

typedef __bf16 bf16;
typedef __attribute__((ext_vector_type(8))) __bf16 bf16x8;
typedef __attribute__((ext_vector_type(4))) float f32x4;

#define SCALE2 (0.08838834764831845f * 1.4426950408889634f)  // log2(e)/sqrt(128)

__device__ inline void gload16(const bf16* g, bf16* l) {
  __builtin_amdgcn_global_load_lds((const __attribute__((address_space(1))) void*)g,
                                   (__attribute__((address_space(3))) void*)l, 16, 0, 0);
}

// ---- prep_all: [0,4096) cvt x->bf16; [4096,4608) rope tables + bias concat;
//      [4608,7168) all 4 weight transposes (Wq|Wk|Wv -> wqkvT, Wo -> woT, own buffer) ----
__global__ __launch_bounds__(256)
void prep_all_kernel(const float* __restrict__ x, bf16* __restrict__ xb,
                     const float* __restrict__ bq, const float* __restrict__ bk,
                     const float* __restrict__ bv, float* __restrict__ bqkv,
                     float* __restrict__ cost, float* __restrict__ sint,
                     const float* __restrict__ Wq, const float* __restrict__ Wk,
                     const float* __restrict__ Wv, const float* __restrict__ Wo,
                     bf16* __restrict__ wqkvT, bf16* __restrict__ woT) {
  __shared__ bf16 tile[64][72];
  int bid = blockIdx.x;
  if (bid < 4096) {
    int i = bid * 256 + threadIdx.x;           // 4096*256 chunks of 8
    const float* p = x + (size_t)i * 8;
    float4 a = *(const float4*)p, b = *(const float4*)(p + 4);
    union { uint4 u; bf16 h[8]; } un;
    un.h[0] = (bf16)a.x; un.h[1] = (bf16)a.y; un.h[2] = (bf16)a.z; un.h[3] = (bf16)a.w;
    un.h[4] = (bf16)b.x; un.h[5] = (bf16)b.y; un.h[6] = (bf16)b.z; un.h[7] = (bf16)b.w;
    *(uint4*)(xb + (size_t)i * 8) = un.u;
  } else if (bid < 4608) {
    int idx = (bid - 4096) * 256 + threadIdx.x;   // 0..131071 = 2048*64
    int t = idx >> 6, i = idx & 63;
    float inv = expf(-(float)i * (logf(10000.f) / 64.f));
    float ang = (float)t * inv;
    cost[idx] = cosf(ang);
    sint[idx] = sinf(ang);
    if (idx < 3072)
      bqkv[idx] = (idx < 2048) ? bq[idx] : (idx < 2560 ? bk[idx - 2048] : bv[idx - 2560]);
  } else {
    int b2 = bid - 4608;             // 0..2559 = 80 x 32
    int by = b2 / 80, bx = b2 - by * 80;
    const float* in; bf16* out; int N, n0;
    const int K = 2048;
    if (bx < 32)      { in = Wq; out = wqkvT;                        N = 2048; n0 = bx * 64; }
    else if (bx < 40) { in = Wk; out = wqkvT + (size_t)2048 * 2048; N = 512;  n0 = (bx - 32) * 64; }
    else if (bx < 48) { in = Wv; out = wqkvT + (size_t)2560 * 2048; N = 512;  n0 = (bx - 40) * 64; }
    else              { in = Wo; out = woT;                          N = 2048; n0 = (bx - 48) * 64; }
    int k0 = by * 64;
    int t = threadIdx.x;
    int r8 = t >> 5, c2 = (t & 31) * 2;
#pragma unroll
    for (int it = 0; it < 8; it++) {
      int row = it * 8 + r8;
      float2 v = *(const float2*)(in + (size_t)(k0 + row) * N + n0 + c2);
      tile[row][c2] = (bf16)v.x;
      tile[row][c2 + 1] = (bf16)v.y;
    }
    __syncthreads();
    int r = t >> 3, c = (t & 7) * 8;
    int rot = t & 7;
#pragma unroll
    for (int it = 0; it < 2; it++) {
      int rr = it * 32 + r;
      union { uint4 u; bf16 h[8]; } un;
#pragma unroll
      for (int j = 0; j < 8; j++) {
        int jj = (j + rot) & 7;
        un.h[jj] = tile[c + jj][rr];   // = in[k0+c+jj][n0+rr]
      }
      *(uint4*)(out + (size_t)(n0 + rr) * K + k0 + c) = un.u;
    }
  }
}

// ---- fused RoPE-apply (blocks <5120) + V transpose (blocks 5120..5631) ----
__global__ __launch_bounds__(256)
void ropev_kernel(bf16* __restrict__ qkv, const float* __restrict__ cost,
                  const float* __restrict__ sint, bf16* __restrict__ vT) {
  __shared__ bf16 tile[64][72];
  if (blockIdx.x < 5120) {
    int p = blockIdx.x * 256 + threadIdx.x;     // 4096*320 chunks of 8 elems
    if (p >= 4096 * 320) return;
    int row = p / 320;
    int rc = p - row * 320;
    int e = rc * 8;
    int t = row & 2047;
    int i0 = (e & 127) >> 1;
    bf16* ptr = qkv + (size_t)row * 3072 + e;
    float4 cv = *(const float4*)(cost + t * 64 + i0);
    float4 sv = *(const float4*)(sint + t * 64 + i0);
    float c[4] = {cv.x, cv.y, cv.z, cv.w}, s[4] = {sv.x, sv.y, sv.z, sv.w};
    union { uint4 u; bf16 h[8]; } un;
    un.u = *(const uint4*)ptr;
#pragma unroll
    for (int j = 0; j < 4; j++) {
      float x0 = (float)un.h[2 * j], x1 = (float)un.h[2 * j + 1];
      un.h[2 * j]     = (bf16)(x0 * c[j] - x1 * s[j]);
      un.h[2 * j + 1] = (bf16)(x1 * c[j] + x0 * s[j]);
    }
    *(uint4*)ptr = un.u;
  } else {
    int bid = blockIdx.x - 5120;     // 0..511
    int z = bid & 7;                 // b*4+kvh
    int yy = (bid >> 3) & 1;
    int xx = bid >> 4;               // 0..31
    int b = z >> 2, kvh = z & 3;
    int d0 = yy * 64;
    int t0 = xx * 64;
    const bf16* in = qkv + (size_t)(b * 2048) * 3072 + 2560 + kvh * 128;
    int t = threadIdx.x;
    int r = t >> 3, c = (t & 7) * 8;
#pragma unroll
    for (int it = 0; it < 2; it++) {
      int rr = it * 32 + r;
      *(uint4*)&tile[rr][c] = *(const uint4*)(in + (size_t)(t0 + rr) * 3072 + d0 + c);
    }
    __syncthreads();
    int rot = t & 7;
#pragma unroll
    for (int it = 0; it < 2; it++) {
      int rr = it * 32 + r;
      union { uint4 u; bf16 h[8]; } un;
#pragma unroll
      for (int j = 0; j < 8; j++) {
        int jj = (j + rot) & 7;
        un.h[jj] = tile[c + jj][rr];
      }
      *(uint4*)(vT + (size_t)(z * 128 + d0 + rr) * 2048 + t0 + c) = un.u;
    }
  }
}

// ---------------- GEMM: BK=32 dbuf + both-sides chunk swizzle + XCD swizzle (r12) ------
template <typename OutT>
__global__ __launch_bounds__(256)
void gemm_bias_kernel(const bf16* __restrict__ A, const bf16* __restrict__ Bt,
                      const float* __restrict__ bias, OutT* __restrict__ C,
                      int M, int N, int K, int lda, int ldc) {
  __shared__ bf16 As[2][128 * 32];
  __shared__ bf16 Bs[2][128 * 32];
  int tid = threadIdx.x;
  int wv = tid >> 6, l = tid & 63;
  int wr = wv >> 1, wc = wv & 1;
  int lr = l & 15, g = l >> 4;

  int bid = blockIdx.y * gridDim.x + blockIdx.x;
  int cpx = (gridDim.x * gridDim.y) >> 3;
  int swz = (bid & 7) * cpx + (bid >> 3);
  int m0 = (swz / gridDim.x) * 128, n0 = (swz % gridDim.x) * 128;

  auto stage = [&](int k0, int buf) {
#pragma unroll
    for (int i = 0; i < 2; i++) {
      int e = i * 256 + tid;
      int row = e >> 2, c = e & 3;
      int csrc = (c ^ ((row >> 1) & 3)) * 8;
      gload16(A + (size_t)(m0 + row) * lda + k0 + csrc, &As[buf][(size_t)e * 8]);
      gload16(Bt + (size_t)(n0 + row) * K + k0 + csrc, &Bs[buf][(size_t)e * 8]);
    }
  };

  f32x4 acc[4][4] = {};
  stage(0, 0);
  __syncthreads();
  int cur = 0;
  int cswz = (g ^ ((lr >> 1) & 3)) * 8;
  for (int k0 = 32; k0 <= K; k0 += 32) {
    if (k0 < K) stage(k0, cur ^ 1);
    bf16x8 a[4], b[4];
#pragma unroll
    for (int mi = 0; mi < 4; mi++)
      a[mi] = *(const bf16x8*)&As[cur][(size_t)(wr * 64 + mi * 16 + lr) * 32 + cswz];
#pragma unroll
    for (int nj = 0; nj < 4; nj++)
      b[nj] = *(const bf16x8*)&Bs[cur][(size_t)(wc * 64 + nj * 16 + lr) * 32 + cswz];
#pragma unroll
    for (int mi = 0; mi < 4; mi++)
#pragma unroll
      for (int nj = 0; nj < 4; nj++)
        acc[mi][nj] = __builtin_amdgcn_mfma_f32_16x16x32_bf16(a[mi], b[nj], acc[mi][nj], 0, 0, 0);
    __syncthreads();
    cur ^= 1;
  }
#pragma unroll
  for (int nj = 0; nj < 4; nj++) {
    int gc = n0 + wc * 64 + nj * 16 + lr;
    float bv = bias[gc];
#pragma unroll
    for (int mi = 0; mi < 4; mi++) {
      int gr = m0 + wr * 64 + mi * 16 + g * 4;
#pragma unroll
      for (int reg = 0; reg < 4; reg++)
        C[(size_t)(gr + reg) * ldc + gc] = (OutT)(acc[mi][nj][reg] + bv);
    }
  }
}

// ---- Flash attention (causal, GQA): r13 structure + pre-scaled Q + setprio (r18/19) ----
__global__ __launch_bounds__(512, 4)
void attn_kernel(const bf16* __restrict__ qkv, const bf16* __restrict__ vT,
                 bf16* __restrict__ ybuf) {
  __shared__ bf16 Ks[64 * 128];       // K single-buf [kpos][d], chunk-swizzled c^=(row&7)
  __shared__ bf16 Vts[2][128 * 64];   // V^T dbuf [d][s], chunk-swizzled c^=(row&7)
  __shared__ bf16 Ps[8][16][72];      // per-wave P tile [q-row][k], padded

  int pair = blockIdx.x;          // 0..15
  int bh = blockIdx.y;            // 0..31
  int b = bh >> 4, h = bh & 15;
  int kvh = h >> 2;               // G=4
  int tid = threadIdx.x, w = tid >> 6, l = tid & 63;
  int lr = l & 15, g = l >> 4, lk = g * 8;
  int wl = w & 3, wg = w >> 2;
  int qt = wg ? pair : 31 - pair;       // group 0 -> long tile
  int q0 = qt * 64;
  int nt = 32 - pair;                   // iterations (max over both groups)

  const bf16* kbase = qkv + (size_t)(b * 2048) * 3072 + 2048 + kvh * 128;
  const bf16* vtb   = vT + (size_t)(b * 4 + kvh) * 128 * 2048;
  f32x4 zero4 = {0.f, 0.f, 0.f, 0.f};

  auto stageK = [&](int kv0) {
#pragma unroll
    for (int it = 0; it < 2; it++) {
      int cidx = it * 512 + tid;
      int row = cidx >> 4, c = cidx & 15, csrc = c ^ (row & 7);
      gload16(kbase + (size_t)(kv0 + row) * 3072 + csrc * 8, &Ks[(size_t)cidx * 8]);
    }
  };
  auto stageV = [&](int kv0, int buf) {
#pragma unroll
    for (int it = 0; it < 2; it++) {
      int cidx = it * 512 + tid;
      int row = cidx >> 3, c = cidx & 7, csrc = c ^ (row & 7);
      gload16(vtb + (size_t)row * 2048 + kv0 + csrc * 8, &Vts[buf][(size_t)cidx * 8]);
    }
  };

  // Q fragments (post-RoPE), pre-scaled by log2(e)/sqrt(D)
  const bf16* qbase = qkv + (size_t)(b * 2048 + q0 + wl * 16 + lr) * 3072 + h * 128;
  bf16x8 qf[4];
#pragma unroll
  for (int kk = 0; kk < 4; kk++) {
    bf16x8 v = *(const bf16x8*)(qbase + kk * 32 + lk);
#pragma unroll
    for (int j = 0; j < 8; j++) v[j] = (bf16)((float)v[j] * SCALE2);
    qf[kk] = v;
  }

  float m_r = -1e30f, l_r = 0.f;      // per-lane scalars (q-row lr)
  f32x4 o_acc[8];
#pragma unroll
  for (int f = 0; f < 8; f++) o_acc[f] = zero4;

  stageK(0);
  stageV(0, 0);
  __syncthreads();                 // drains vmcnt(0): tile 0 resident
  int cur = 0;

  for (int kvt = 0; kvt < nt; kvt++) {
    int kv0 = kvt * 64;
    bool act = (kvt <= qt);        // wave-uniform

    f32x4 sa[4];
#pragma unroll
    for (int nj = 0; nj < 4; nj++) sa[nj] = zero4;
    if (act) {
      __builtin_amdgcn_s_setprio(1);
#pragma unroll
      for (int kk = 0; kk < 4; kk++) {
        int cmem = (kk * 4 + g) ^ (lr & 7);
#pragma unroll
        for (int nj = 0; nj < 4; nj++) {
          bf16x8 kf = *(const bf16x8*)&Ks[(size_t)((nj * 16 + lr) * 16 + cmem) * 8];
          sa[nj] = __builtin_amdgcn_mfma_f32_16x16x32_bf16(kf, qf[kk], sa[nj], 0, 0, 0);
        }
      }
      __builtin_amdgcn_s_setprio(0);
    }
    __syncthreads();               // barA: all QK reads of Ks done

    if (kvt + 1 < nt) {
      stageK(kv0 + 64);
      stageV(kv0 + 64, cur ^ 1);
    }

    if (act) {
      bool diag = (kvt == qt);
      int qpos = q0 + wl * 16 + lr;
      float p[4][4];
#pragma unroll
      for (int nj = 0; nj < 4; nj++)
#pragma unroll
        for (int rg = 0; rg < 4; rg++) {
          float s = sa[nj][rg];
          if (diag && (kv0 + nj * 16 + g * 4 + rg > qpos)) s = -1e30f;
          p[nj][rg] = s;
        }

      float a0 = fmaxf(fmaxf(p[0][0], p[0][1]), fmaxf(p[0][2], p[0][3]));
      float a1 = fmaxf(fmaxf(p[1][0], p[1][1]), fmaxf(p[1][2], p[1][3]));
      float a2 = fmaxf(fmaxf(p[2][0], p[2][1]), fmaxf(p[2][2], p[2][3]));
      float a3 = fmaxf(fmaxf(p[3][0], p[3][1]), fmaxf(p[3][2], p[3][3]));
      float mx = fmaxf(fmaxf(a0, a1), fmaxf(a2, a3));
      mx = fmaxf(mx, __shfl_xor(mx, 16));
      mx = fmaxf(mx, __shfl_xor(mx, 32));

      if (__any(mx > m_r + 8.0f)) {
        float mnew = fmaxf(m_r, mx);
        float sc = exp2f(m_r - mnew);
        l_r *= sc;
        m_r = mnew;
        float osc[4];
#pragma unroll
        for (int rg = 0; rg < 4; rg++) osc[rg] = __shfl(sc, g * 4 + rg);
#pragma unroll
        for (int f = 0; f < 8; f++)
#pragma unroll
          for (int rg = 0; rg < 4; rg++) o_acc[f][rg] *= osc[rg];
      }

#pragma unroll
      for (int nj = 0; nj < 4; nj++)
#pragma unroll
        for (int rg = 0; rg < 4; rg++) p[nj][rg] = exp2f(p[nj][rg] - m_r);
      float s0 = (p[0][0] + p[0][1]) + (p[0][2] + p[0][3]);
      float s1 = (p[1][0] + p[1][1]) + (p[1][2] + p[1][3]);
      float s2 = (p[2][0] + p[2][1]) + (p[2][2] + p[2][3]);
      float s3 = (p[3][0] + p[3][1]) + (p[3][2] + p[3][3]);
      float rs = (s0 + s1) + (s2 + s3);
      rs += __shfl_xor(rs, 16);
      rs += __shfl_xor(rs, 32);
      l_r += rs;

#pragma unroll
      for (int nj = 0; nj < 4; nj++) {
        union { uint2 u; bf16 hh[4]; } pw;
#pragma unroll
        for (int rg = 0; rg < 4; rg++) pw.hh[rg] = (bf16)p[nj][rg];
        *(uint2*)&Ps[w][lr][nj * 16 + g * 4] = pw.u;
      }
      asm volatile("s_waitcnt lgkmcnt(0)" ::: "memory");
      __builtin_amdgcn_sched_barrier(0);

      __builtin_amdgcn_s_setprio(1);
#pragma unroll
      for (int kk2 = 0; kk2 < 2; kk2++) {
        bf16x8 pf = *(const bf16x8*)&Ps[w][lr][kk2 * 32 + lk];
        int cmem = (kk2 * 4 + g) ^ (lr & 7);
#pragma unroll
        for (int f = 0; f < 8; f++) {
          bf16x8 vf = *(const bf16x8*)&Vts[cur][(size_t)((f * 16 + lr) * 8 + cmem) * 8];
          o_acc[f] = __builtin_amdgcn_mfma_f32_16x16x32_bf16(pf, vf, o_acc[f], 0, 0, 0);
        }
      }
      __builtin_amdgcn_s_setprio(0);
    }
    __syncthreads();               // barB: drains next-tile DMA; PV reads done
    cur ^= 1;
  }

  float linv[4];
#pragma unroll
  for (int rg = 0; rg < 4; rg++) linv[rg] = 1.0f / __shfl(l_r, g * 4 + rg);
  size_t orow = (size_t)(b * 2048 + q0 + wl * 16);
#pragma unroll
  for (int rg = 0; rg < 4; rg++) {
    int r = g * 4 + rg;
#pragma unroll
    for (int f = 0; f < 8; f++) {
      float ov = o_acc[f][rg] * linv[rg];
      ybuf[(orow + r) * 2048 + h * 128 + f * 16 + lr] = (bf16)ov;
    }
  }
}

// ---------------- host launch: 5 dispatches (was 7) ----------------
extern "C" void kernel_launch(void* const* d_in, const int* in_sizes, int n_in,
                              void* d_out, int out_size, void* d_ws, size_t ws_size,
                              hipStream_t stream) {
  const float* x  = (const float*)d_in[0];
  const float* Wq = (const float*)d_in[1];
  const float* bq = (const float*)d_in[2];
  const float* Wk = (const float*)d_in[3];
  const float* bk = (const float*)d_in[4];
  const float* Wv = (const float*)d_in[5];
  const float* bv = (const float*)d_in[6];
  const float* Wo = (const float*)d_in[7];
  const float* bo = (const float*)d_in[8];
  float* out = (float*)d_out;

  // ws ~68.2 MB (r2 proved >=81 MB works: identical result at 81 MB layout)
  char* w = (char*)d_ws;
  auto alloc = [&](size_t bytes) { char* p = w; w += (bytes + 255) & ~(size_t)255; return p; };
  bf16*  xb    = (bf16*)alloc((size_t)4096 * 2048 * 2);
  bf16*  wqkvT = (bf16*)alloc((size_t)3072 * 2048 * 2);
  bf16*  woT   = (bf16*)alloc((size_t)2048 * 2048 * 2);      // own buffer (no alias)
  bf16*  qkv   = (bf16*)alloc((size_t)4096 * 3072 * 2);
  bf16*  vTg   = (bf16*)alloc((size_t)8 * 128 * 2048 * 2);   // [b*4+kvh][128][2048]
  float* bqkv  = (float*)alloc((size_t)3072 * 4);
  float* cost  = (float*)alloc((size_t)2048 * 64 * 4);
  float* sint  = (float*)alloc((size_t)2048 * 64 * 4);
  bf16*  ybuf  = xb;      // alias: xb dead before attn writes ybuf

  prep_all_kernel<<<7168, 256, 0, stream>>>(x, xb, bq, bk, bv, bqkv, cost, sint,
                                            Wq, Wk, Wv, Wo, wqkvT, woT);
  gemm_bias_kernel<bf16><<<dim3(24, 32), 256, 0, stream>>>(xb, wqkvT, bqkv, qkv, 4096, 3072, 2048, 2048, 3072);
  ropev_kernel<<<5632, 256, 0, stream>>>(qkv, cost, sint, vTg);
  attn_kernel<<<dim3(16, 32), 512, 0, stream>>>(qkv, vTg, ybuf);
  gemm_bias_kernel<float><<<dim3(16, 32), 256, 0, stream>>>(ybuf, woT, bo, out, 4096, 2048, 2048, 2048, 2048);
}